// Round 1
// baseline (3428.120 us; speedup 1.0000x reference)
//
#include <hip/hip_runtime.h>
#include <hip/hip_bf16.h>
#include <math.h>

#define N_NODES 50000
#define N_EDGES 1600000
#define NODE_IN 128
#define HID 64
#define NODEF (N_NODES * HID)   // 3,200,000 floats per node buffer

// ---------------- dual GEMM: out1 = in @ Wa, out2 = in @ Wb ; in [N,K], W [K,64]
template <int K>
__global__ __launch_bounds__(256) void dual_mm(const float* __restrict__ in,
                                               const float* __restrict__ Wa,
                                               const float* __restrict__ Wb,
                                               float* __restrict__ out1,
                                               float* __restrict__ out2, int N) {
    __shared__ float xs[4][K];
    const int row0 = blockIdx.x * 4;
    const int ty = threadIdx.x >> 6;    // 0..3 (row within tile)
    const int col = threadIdx.x & 63;   // 0..63 (output column)
    for (int i = threadIdx.x; i < 4 * K; i += 256) {
        int r = i / K, c = i % K;
        int row = row0 + r;
        xs[r][c] = (row < N) ? in[row * K + c] : 0.f;
    }
    __syncthreads();
    float acc1 = 0.f, acc2 = 0.f;
#pragma unroll 8
    for (int k = 0; k < K; ++k) {
        float xv = xs[ty][k];
        acc1 = fmaf(xv, Wa[k * 64 + col], acc1);
        acc2 = fmaf(xv, Wb[k * 64 + col], acc2);
    }
    const int row = row0 + ty;
    if (row < N) {
        out1[row * 64 + col] = acc1;
        out2[row * 64 + col] = acc2;
    }
}

// ---------------- degree count: deg[dst[e]] += 1
__global__ __launch_bounds__(256) void deg_count(const int* __restrict__ dst,
                                                 float* __restrict__ deg, int E) {
    int e = blockIdx.x * blockDim.x + threadIdx.x;
    if (e < E) unsafeAtomicAdd(&deg[dst[e]], 1.0f);
}

// ---------------- scatter: agg[dst[e]] += y[src[e]]  (16 threads/edge, 4 feats each)
__global__ __launch_bounds__(256) void scatter_add(const float* __restrict__ y,
                                                   const int* __restrict__ src,
                                                   const int* __restrict__ dst,
                                                   float* __restrict__ agg, int E) {
    int t = blockIdx.x * blockDim.x + threadIdx.x;
    int e = t >> 4;
    if (e >= E) return;
    int q = (t & 15) * 4;
    int s = src[e], d = dst[e];
    const float4 v = *reinterpret_cast<const float4*>(y + (size_t)s * 64 + q);
    float* a = agg + (size_t)d * 64 + q;
    unsafeAtomicAdd(a + 0, v.x);
    unsafeAtomicAdd(a + 1, v.y);
    unsafeAtomicAdd(a + 2, v.z);
    unsafeAtomicAdd(a + 3, v.w);
}

// ---------------- combine: h = ReLU(agg/max(deg,1) + bias + r)
__global__ __launch_bounds__(256) void combine(const float* __restrict__ agg,
                                               const float* __restrict__ r,
                                               const float* __restrict__ deg,
                                               const float* __restrict__ bias,
                                               float* __restrict__ h, int N) {
    int i = blockIdx.x * blockDim.x + threadIdx.x;
    if (i >= N * 64) return;
    int node = i >> 6, col = i & 63;
    float m = agg[i] / fmaxf(deg[node], 1.0f);
    h[i] = fmaxf(m + bias[col] + r[i], 0.f);
}

// ---------------- edge MLP: one 64-lane wave per edge
__global__ __launch_bounds__(256) void edge_mlp(const float* __restrict__ aE,
                                                const float* __restrict__ bE,
                                                const float* __restrict__ ea,
                                                const float* __restrict__ Wbot,
                                                const float* __restrict__ bm1,
                                                const float* __restrict__ wm2,
                                                const float* __restrict__ bm2,
                                                const int* __restrict__ src,
                                                const int* __restrict__ dst,
                                                float* __restrict__ out, int E) {
    long long t = (long long)blockIdx.x * blockDim.x + threadIdx.x;
    int e = (int)(t >> 6);
    if (e >= E) return;
    int j = (int)(t & 63);
    int s = src[e], d = dst[e];
    float v = aE[(size_t)s * 64 + j] + bE[(size_t)d * 64 + j] + bm1[j];
    float eav = (j < 16) ? ea[(size_t)e * 16 + j] : 0.f;
#pragma unroll
    for (int k = 0; k < 16; ++k) {
        v = fmaf(__shfl(eav, k, 64), Wbot[k * 64 + j], v);
    }
    v = fmaxf(v, 0.f);
    float p = v * wm2[j];
#pragma unroll
    for (int off = 32; off; off >>= 1) p += __shfl_xor(p, off, 64);
    if (j == 0) out[e] = 1.f / (1.f + expf(-(p + bm2[0])));
}

extern "C" void kernel_launch(void* const* d_in, const int* in_sizes, int n_in,
                              void* d_out, int out_size, void* d_ws, size_t ws_size,
                              hipStream_t stream) {
    const float* x         = (const float*)d_in[0];
    const float* edge_attr = (const float*)d_in[1];
    const float* W1l       = (const float*)d_in[2];
    const float* b1l       = (const float*)d_in[3];
    const float* W1r       = (const float*)d_in[4];
    const float* W2l       = (const float*)d_in[5];
    const float* b2l       = (const float*)d_in[6];
    const float* W2r       = (const float*)d_in[7];
    const float* Wm1       = (const float*)d_in[8];
    const float* bm1       = (const float*)d_in[9];
    const float* Wm2       = (const float*)d_in[10];
    const float* bm2       = (const float*)d_in[11];
    const int*   ei        = (const int*)d_in[12];   // [2, E] int32
    const int*   src       = ei;
    const int*   dst       = ei + N_EDGES;
    float* out = (float*)d_out;

    float* ws   = (float*)d_ws;
    float* deg  = ws;                 // 50000 floats (padded to 50176)
    float* bufA = ws + 50176;         // node buffers, 3.2M floats each
    float* bufB = bufA + NODEF;
    float* bufC = bufB + NODEF;
    float* bufD = bufC + NODEF;

    const int N = N_NODES, E = N_EDGES;
    const int mmGrid  = (N + 3) / 4;                 // 12500
    const int egGrid  = (E + 255) / 256;             // deg
    const int scGrid  = (E * 16 + 255) / 256;        // scatter (25.6M threads)
    const int cbGrid  = (N * 64 + 255) / 256;        // combine
    const long long emThreads = (long long)E * 64;
    const int emGrid  = (int)((emThreads + 255) / 256);

    // ---- conv1
    hipMemsetAsync(deg, 0, N_NODES * sizeof(float), stream);
    hipMemsetAsync(bufC, 0, (size_t)NODEF * sizeof(float), stream);
    deg_count<<<egGrid, 256, 0, stream>>>(dst, deg, E);
    dual_mm<128><<<mmGrid, 256, 0, stream>>>(x, W1l, W1r, bufA, bufB, N);   // y1, r1
    scatter_add<<<scGrid, 256, 0, stream>>>(bufA, src, dst, bufC, E);       // agg1
    combine<<<cbGrid, 256, 0, stream>>>(bufC, bufB, deg, b1l, bufD, N);     // h1 -> D

    // ---- conv2
    dual_mm<64><<<mmGrid, 256, 0, stream>>>(bufD, W2l, W2r, bufA, bufB, N); // y2, r2
    hipMemsetAsync(bufC, 0, (size_t)NODEF * sizeof(float), stream);
    scatter_add<<<scGrid, 256, 0, stream>>>(bufA, src, dst, bufC, E);       // agg2
    combine<<<cbGrid, 256, 0, stream>>>(bufC, bufB, deg, b2l, bufA, N);     // h2 -> A

    // ---- edge precompute: aE = h2 @ Wm1[0:64], bE = h2 @ Wm1[64:128]
    dual_mm<64><<<mmGrid, 256, 0, stream>>>(bufA, Wm1, Wm1 + 64 * 64, bufB, bufD, N);

    // ---- edge MLP
    edge_mlp<<<emGrid, 256, 0, stream>>>(bufB, bufD, edge_attr, Wm1 + 128 * 64,
                                         bm1, Wm2, bm2, src, dst, out, E);
}

// Round 2
// 1137.098 us; speedup vs baseline: 3.0148x; 3.0148x over previous
//
#include <hip/hip_runtime.h>
#include <hip/hip_bf16.h>
#include <math.h>

#define N_NODES 50000
#define N_EDGES 1600000
#define NODE_IN 128
#define HID 64
#define NODEF (N_NODES * HID)   // 3,200,000 floats per node buffer

// ---------------- dual GEMM: out1 = in @ Wa, out2 = in @ Wb ; in [N,K], W [K,64]
template <int K>
__global__ __launch_bounds__(256) void dual_mm(const float* __restrict__ in,
                                               const float* __restrict__ Wa,
                                               const float* __restrict__ Wb,
                                               float* __restrict__ out1,
                                               float* __restrict__ out2, int N) {
    __shared__ float xs[4][K];
    const int row0 = blockIdx.x * 4;
    const int ty = threadIdx.x >> 6;    // 0..3 (row within tile)
    const int col = threadIdx.x & 63;   // 0..63 (output column)
    for (int i = threadIdx.x; i < 4 * K; i += 256) {
        int r = i / K, c = i % K;
        int row = row0 + r;
        xs[r][c] = (row < N) ? in[row * K + c] : 0.f;
    }
    __syncthreads();
    float acc1 = 0.f, acc2 = 0.f;
#pragma unroll 8
    for (int k = 0; k < K; ++k) {
        float xv = xs[ty][k];
        acc1 = fmaf(xv, Wa[k * 64 + col], acc1);
        acc2 = fmaf(xv, Wb[k * 64 + col], acc2);
    }
    const int row = row0 + ty;
    if (row < N) {
        out1[row * 64 + col] = acc1;
        out2[row * 64 + col] = acc2;
    }
}

// ---------------- CSR build step 1: integer degree count
__global__ __launch_bounds__(256) void deg_count_i(const int* __restrict__ dst,
                                                   int* __restrict__ degi, int E) {
    int e = blockIdx.x * blockDim.x + threadIdx.x;
    if (e < E) atomicAdd(&degi[dst[e]], 1);
}

// ---------------- CSR build step 2: exclusive scan over 50K degrees (single block)
__global__ __launch_bounds__(1024) void scan_offsets(const int* __restrict__ degi,
                                                     int* __restrict__ off,
                                                     int* __restrict__ cursor, int N) {
    __shared__ int part[1024];
    const int T = 1024;
    const int chunk = (N + T - 1) / T;
    const int t = threadIdx.x;
    const int lo = t * chunk;
    const int hi = min(lo + chunk, N);
    int s = 0;
    for (int i = lo; i < hi; ++i) s += degi[i];
    part[t] = s;
    __syncthreads();
    // Hillis-Steele inclusive scan
    for (int d = 1; d < T; d <<= 1) {
        int u = (t >= d) ? part[t - d] : 0;
        __syncthreads();
        part[t] += u;
        __syncthreads();
    }
    int run = part[t] - s;   // exclusive base for this chunk
    for (int i = lo; i < hi; ++i) {
        off[i] = run;
        cursor[i] = run;
        run += degi[i];
    }
    if (t == T - 1) off[N] = part[T - 1];
}

// ---------------- CSR build step 3: place src ids
__global__ __launch_bounds__(256) void fill_csr(const int* __restrict__ src,
                                                const int* __restrict__ dst,
                                                int* __restrict__ cursor,
                                                int* __restrict__ csr, int E) {
    int e = blockIdx.x * blockDim.x + threadIdx.x;
    if (e < E) {
        int p = atomicAdd(&cursor[dst[e]], 1);
        csr[p] = src[e];
    }
}

// ---------------- gather + combine: h = ReLU(mean_{s in N(d)} y[s] + bias + r)
__global__ __launch_bounds__(256) void gather_combine(const float* __restrict__ y,
                                                      const float* __restrict__ r,
                                                      const int* __restrict__ csr,
                                                      const int* __restrict__ off,
                                                      const float* __restrict__ bias,
                                                      float* __restrict__ h, int N) {
    int t = blockIdx.x * blockDim.x + threadIdx.x;
    int node = t >> 6;
    if (node >= N) return;
    int j = t & 63;
    int s0 = off[node], s1 = off[node + 1];
    float acc = 0.f;
    for (int k = s0; k < s1; ++k) {
        int s = csr[k];                       // wave-uniform, L1-broadcast
        acc += y[(size_t)s * 64 + j];         // coalesced 256B row read
    }
    float m = acc / fmaxf((float)(s1 - s0), 1.f);
    h[t] = fmaxf(m + bias[j] + r[t], 0.f);
}

// ---------------- edge MLP: one 64-lane wave per edge
__global__ __launch_bounds__(256) void edge_mlp(const float* __restrict__ aE,
                                                const float* __restrict__ bE,
                                                const float* __restrict__ ea,
                                                const float* __restrict__ Wbot,
                                                const float* __restrict__ bm1,
                                                const float* __restrict__ wm2,
                                                const float* __restrict__ bm2,
                                                const int* __restrict__ src,
                                                const int* __restrict__ dst,
                                                float* __restrict__ out, int E) {
    long long t = (long long)blockIdx.x * blockDim.x + threadIdx.x;
    int e = (int)(t >> 6);
    if (e >= E) return;
    int j = (int)(t & 63);
    int s = src[e], d = dst[e];
    float v = aE[(size_t)s * 64 + j] + bE[(size_t)d * 64 + j] + bm1[j];
    float eav = (j < 16) ? ea[(size_t)e * 16 + j] : 0.f;
#pragma unroll
    for (int k = 0; k < 16; ++k) {
        v = fmaf(__shfl(eav, k, 64), Wbot[k * 64 + j], v);
    }
    v = fmaxf(v, 0.f);
    float p = v * wm2[j];
#pragma unroll
    for (int off = 32; off; off >>= 1) p += __shfl_xor(p, off, 64);
    if (j == 0) out[e] = 1.f / (1.f + expf(-(p + bm2[0])));
}

extern "C" void kernel_launch(void* const* d_in, const int* in_sizes, int n_in,
                              void* d_out, int out_size, void* d_ws, size_t ws_size,
                              hipStream_t stream) {
    const float* x         = (const float*)d_in[0];
    const float* edge_attr = (const float*)d_in[1];
    const float* W1l       = (const float*)d_in[2];
    const float* b1l       = (const float*)d_in[3];
    const float* W1r       = (const float*)d_in[4];
    const float* W2l       = (const float*)d_in[5];
    const float* b2l       = (const float*)d_in[6];
    const float* W2r       = (const float*)d_in[7];
    const float* Wm1       = (const float*)d_in[8];
    const float* bm1       = (const float*)d_in[9];
    const float* Wm2       = (const float*)d_in[10];
    const float* bm2       = (const float*)d_in[11];
    const int*   ei        = (const int*)d_in[12];   // [2, E] int32
    const int*   src       = ei;
    const int*   dst       = ei + N_EDGES;
    float* out = (float*)d_out;

    // workspace layout (words): degi 50176 | off 50432 | cursor 50176 | csr 1.6M | 3 node bufs
    int*   degi   = (int*)d_ws;
    int*   off    = degi + 50176;
    int*   cursor = off + 50432;
    int*   csr    = cursor + 50176;
    float* bufA   = (float*)(csr + N_EDGES);
    float* bufB   = bufA + NODEF;
    float* bufC   = bufB + NODEF;

    const int N = N_NODES, E = N_EDGES;
    const int egGrid = (E + 255) / 256;
    const int mmGrid = (N + 3) / 4;
    const int gcGrid = (N * 64 + 255) / 256;
    const long long emThreads = (long long)E * 64;
    const int emGrid = (int)((emThreads + 255) / 256);

    // ---- CSR build (shared by both convs)
    hipMemsetAsync(degi, 0, N_NODES * sizeof(int), stream);
    deg_count_i<<<egGrid, 256, 0, stream>>>(dst, degi, E);
    scan_offsets<<<1, 1024, 0, stream>>>(degi, off, cursor, N);
    fill_csr<<<egGrid, 256, 0, stream>>>(src, dst, cursor, csr, E);

    // ---- conv1
    dual_mm<128><<<mmGrid, 256, 0, stream>>>(x, W1l, W1r, bufA, bufB, N);      // y1, r1
    gather_combine<<<gcGrid, 256, 0, stream>>>(bufA, bufB, csr, off, b1l, bufC, N);  // h1

    // ---- conv2
    dual_mm<64><<<mmGrid, 256, 0, stream>>>(bufC, W2l, W2r, bufA, bufB, N);    // y2, r2
    gather_combine<<<gcGrid, 256, 0, stream>>>(bufA, bufB, csr, off, b2l, bufC, N);  // h2

    // ---- edge precompute: aE = h2 @ Wm1[0:64], bE = h2 @ Wm1[64:128]
    dual_mm<64><<<mmGrid, 256, 0, stream>>>(bufC, Wm1, Wm1 + 64 * 64, bufA, bufB, N);

    // ---- edge MLP
    edge_mlp<<<emGrid, 256, 0, stream>>>(bufA, bufB, edge_attr, Wm1 + 128 * 64,
                                         bm1, Wm2, bm2, src, dst, out, E);
}

// Round 3
// 951.701 us; speedup vs baseline: 3.6021x; 1.1948x over previous
//
#include <hip/hip_runtime.h>
#include <hip/hip_bf16.h>
#include <math.h>

#define N_NODES 50000
#define N_EDGES 1600000
#define NODE_IN 128
#define HID 64
#define NODEF (N_NODES * HID)   // 3,200,000 elements per node buffer

typedef __hip_bfloat16 bf16;

__device__ __forceinline__ float bf2f(bf16 v) { return __bfloat162float(v); }
__device__ __forceinline__ bf16 f2bf(float v) { return __float2bfloat16(v); }

// ---------------- dual GEMM: out1 = in @ Wa, out2 = in @ Wb ; in [N,K], W [K,64]
// 32 rows per block; each thread owns one output column for 8 rows.
template <int K, bool OUT1_BF, bool OUT2_BF>
__global__ __launch_bounds__(256) void dual_mm(const float* __restrict__ in,
                                               const float* __restrict__ Wa,
                                               const float* __restrict__ Wb,
                                               void* __restrict__ out1v,
                                               void* __restrict__ out2v, int N) {
    constexpr int ROWS = 32;
    __shared__ float xs[ROWS][K];
    const int row0 = blockIdx.x * ROWS;
    const int ty = threadIdx.x >> 6;    // 0..3
    const int col = threadIdx.x & 63;   // 0..63
    for (int i = threadIdx.x; i < ROWS * K; i += 256) {
        int r = i / K, c = i % K;
        int row = row0 + r;
        xs[r][c] = (row < N) ? in[(size_t)row * K + c] : 0.f;
    }
    __syncthreads();
    float a1[8], a2[8];
#pragma unroll
    for (int m = 0; m < 8; ++m) { a1[m] = 0.f; a2[m] = 0.f; }
#pragma unroll 4
    for (int k = 0; k < K; ++k) {
        float wa = Wa[k * 64 + col];
        float wb = Wb[k * 64 + col];
#pragma unroll
        for (int m = 0; m < 8; ++m) {
            float xv = xs[ty + m * 4][k];
            a1[m] = fmaf(xv, wa, a1[m]);
            a2[m] = fmaf(xv, wb, a2[m]);
        }
    }
#pragma unroll
    for (int m = 0; m < 8; ++m) {
        int row = row0 + ty + m * 4;
        if (row < N) {
            unsigned idx = ((unsigned)row << 6) + col;
            if (OUT1_BF) ((bf16*)out1v)[idx] = f2bf(a1[m]);
            else         ((float*)out1v)[idx] = a1[m];
            if (OUT2_BF) ((bf16*)out2v)[idx] = f2bf(a2[m]);
            else         ((float*)out2v)[idx] = a2[m];
        }
    }
}

// ---------------- CSR build step 1: integer degree count
__global__ __launch_bounds__(256) void deg_count_i(const int* __restrict__ dst,
                                                   int* __restrict__ degi, int E) {
    int e = blockIdx.x * blockDim.x + threadIdx.x;
    if (e < E) atomicAdd(&degi[dst[e]], 1);
}

// ---------------- CSR build step 2: exclusive scan over 50K degrees (single block)
__global__ __launch_bounds__(1024) void scan_offsets(const int* __restrict__ degi,
                                                     int* __restrict__ off,
                                                     int* __restrict__ cursor, int N) {
    __shared__ int part[1024];
    const int T = 1024;
    const int chunk = (N + T - 1) / T;
    const int t = threadIdx.x;
    const int lo = t * chunk;
    const int hi = min(lo + chunk, N);
    int s = 0;
    for (int i = lo; i < hi; ++i) s += degi[i];
    part[t] = s;
    __syncthreads();
    for (int d = 1; d < T; d <<= 1) {
        int u = (t >= d) ? part[t - d] : 0;
        __syncthreads();
        part[t] += u;
        __syncthreads();
    }
    int run = part[t] - s;
    for (int i = lo; i < hi; ++i) {
        off[i] = run;
        cursor[i] = run;
        run += degi[i];
    }
    if (t == T - 1) off[N] = part[T - 1];
}

// ---------------- CSR build step 3: place src ids
__global__ __launch_bounds__(256) void fill_csr(const int* __restrict__ src,
                                                const int* __restrict__ dst,
                                                int* __restrict__ cursor,
                                                int* __restrict__ csr, int E) {
    int e = blockIdx.x * blockDim.x + threadIdx.x;
    if (e < E) {
        int p = atomicAdd(&cursor[dst[e]], 1);
        csr[p] = src[e];
    }
}

// ---------------- gather + combine: h = ReLU(mean_{s in N(d)} y[s] + bias + r)
__global__ __launch_bounds__(256) void gather_combine(const bf16* __restrict__ y,
                                                      const float* __restrict__ r,
                                                      const int* __restrict__ csr,
                                                      const int* __restrict__ off,
                                                      const float* __restrict__ bias,
                                                      float* __restrict__ h, int N) {
    int t = blockIdx.x * blockDim.x + threadIdx.x;
    int node = t >> 6;
    if (node >= N) return;
    int j = t & 63;
    int s0 = off[node], s1 = off[node + 1];
    float acc = 0.f;
    int k = s0;
    for (; k + 3 < s1; k += 4) {
        int sa = csr[k], sb = csr[k + 1], sc = csr[k + 2], sd = csr[k + 3];
        float va = bf2f(y[((unsigned)sa << 6) + j]);
        float vb = bf2f(y[((unsigned)sb << 6) + j]);
        float vc = bf2f(y[((unsigned)sc << 6) + j]);
        float vd = bf2f(y[((unsigned)sd << 6) + j]);
        acc += (va + vb) + (vc + vd);
    }
    for (; k < s1; ++k)
        acc += bf2f(y[((unsigned)csr[k] << 6) + j]);
    float m = acc / fmaxf((float)(s1 - s0), 1.f);
    h[t] = fmaxf(m + bias[j] + r[t], 0.f);
}

// ---------------- edge MLP: one 64-lane wave per edge
__global__ __launch_bounds__(256) void edge_mlp(const bf16* __restrict__ aE,
                                                const bf16* __restrict__ bE,
                                                const float* __restrict__ ea,
                                                const float* __restrict__ Wbot,
                                                const float* __restrict__ bm1,
                                                const float* __restrict__ wm2,
                                                const float* __restrict__ bm2,
                                                const int* __restrict__ src,
                                                const int* __restrict__ dst,
                                                float* __restrict__ out, int E) {
    long long t = (long long)blockIdx.x * blockDim.x + threadIdx.x;
    int e = (int)(t >> 6);
    if (e >= E) return;
    int j = (int)(t & 63);
    int s = src[e], d = dst[e];                      // wave-uniform broadcast loads
    float v = bf2f(aE[((unsigned)s << 6) + j]) +
              bf2f(bE[((unsigned)d << 6) + j]) + bm1[j];
    const float* eap = ea + (unsigned)e * 16u;       // wave-uniform row
#pragma unroll
    for (int k = 0; k < 16; ++k)
        v = fmaf(eap[k], Wbot[k * 64 + j], v);       // eap[k]: broadcast L1 hit
    v = fmaxf(v, 0.f);
    float p = v * wm2[j];
#pragma unroll
    for (int off = 32; off; off >>= 1) p += __shfl_xor(p, off, 64);
    if (j == 0) out[e] = 1.f / (1.f + __expf(-(p + bm2[0])));
}

extern "C" void kernel_launch(void* const* d_in, const int* in_sizes, int n_in,
                              void* d_out, int out_size, void* d_ws, size_t ws_size,
                              hipStream_t stream) {
    const float* x         = (const float*)d_in[0];
    const float* edge_attr = (const float*)d_in[1];
    const float* W1l       = (const float*)d_in[2];
    const float* b1l       = (const float*)d_in[3];
    const float* W1r       = (const float*)d_in[4];
    const float* W2l       = (const float*)d_in[5];
    const float* b2l       = (const float*)d_in[6];
    const float* W2r       = (const float*)d_in[7];
    const float* Wm1       = (const float*)d_in[8];
    const float* bm1       = (const float*)d_in[9];
    const float* Wm2       = (const float*)d_in[10];
    const float* bm2       = (const float*)d_in[11];
    const int*   ei        = (const int*)d_in[12];   // [2, E] int32
    const int*   src       = ei;
    const int*   dst       = ei + N_EDGES;
    float* out = (float*)d_out;

    // workspace words: degi 50176 | off 50432 | cursor 50176 | csr 1.6M |
    //                  bfA 1.6M (bf16 x 3.2M) | bfB 1.6M | fR 3.2M | fH 3.2M
    int*   degi   = (int*)d_ws;
    int*   off    = degi + 50176;
    int*   cursor = off + 50432;
    int*   csr    = cursor + 50176;
    bf16*  bfA    = (bf16*)(csr + N_EDGES);          // y1 / y2 / aE (bf16)
    bf16*  bfB    = bfA + NODEF;                     // bE (bf16)
    float* fR     = (float*)(bfB + NODEF);           // r1 / r2 (f32)
    float* fH     = fR + NODEF;                      // h1 / h2 (f32)

    const int N = N_NODES, E = N_EDGES;
    const int egGrid = (E + 255) / 256;
    const int mmGrid = (N + 31) / 32;
    const int gcGrid = (N * 64 + 255) / 256;
    const long long emThreads = (long long)E * 64;
    const int emGrid = (int)((emThreads + 255) / 256);

    // ---- CSR build (shared by both convs)
    hipMemsetAsync(degi, 0, N_NODES * sizeof(int), stream);
    deg_count_i<<<egGrid, 256, 0, stream>>>(dst, degi, E);
    scan_offsets<<<1, 1024, 0, stream>>>(degi, off, cursor, N);
    fill_csr<<<egGrid, 256, 0, stream>>>(src, dst, cursor, csr, E);

    // ---- conv1: y1(bf16) = x@W1l, r1(f32) = x@W1r
    dual_mm<128, true, false><<<mmGrid, 256, 0, stream>>>(x, W1l, W1r, bfA, fR, N);
    gather_combine<<<gcGrid, 256, 0, stream>>>(bfA, fR, csr, off, b1l, fH, N);   // h1

    // ---- conv2
    dual_mm<64, true, false><<<mmGrid, 256, 0, stream>>>(fH, W2l, W2r, bfA, fR, N);
    gather_combine<<<gcGrid, 256, 0, stream>>>(bfA, fR, csr, off, b2l, fH, N);   // h2

    // ---- edge precompute: aE(bf16) = h2 @ Wm1[0:64], bE(bf16) = h2 @ Wm1[64:128]
    dual_mm<64, true, true><<<mmGrid, 256, 0, stream>>>(fH, Wm1, Wm1 + 64 * 64, bfA, bfB, N);

    // ---- edge MLP
    edge_mlp<<<emGrid, 256, 0, stream>>>(bfA, bfB, edge_attr, Wm1 + 128 * 64,
                                         bm1, Wm2, bm2, src, dst, out, E);
}

// Round 4
// 746.841 us; speedup vs baseline: 4.5902x; 1.2743x over previous
//
#include <hip/hip_runtime.h>
#include <hip/hip_bf16.h>
#include <math.h>

#define N_NODES 50000
#define N_EDGES 1600000
#define NODE_IN 128
#define HID 64
#define NODEF (N_NODES * HID)   // 3,200,000 elements per node buffer
#define EBLK 128                // edges per block in edge_fused (E % EBLK == 0)

typedef __hip_bfloat16 bf16;

__device__ __forceinline__ float bf2f(bf16 v) { return __bfloat162float(v); }
__device__ __forceinline__ bf16 f2bf(float v) { return __float2bfloat16(v); }

// ---------------- dual GEMM: out1 = in @ Wa, out2 = in @ Wb ; in [N,K], W [K,64]
// 32 rows per block; each thread owns one output column for 8 rows.
template <int K, bool OUT1_BF, bool OUT2_BF>
__global__ __launch_bounds__(256) void dual_mm(const float* __restrict__ in,
                                               const float* __restrict__ Wa,
                                               const float* __restrict__ Wb,
                                               void* __restrict__ out1v,
                                               void* __restrict__ out2v, int N) {
    constexpr int ROWS = 32;
    __shared__ float xs[ROWS][K];
    const int row0 = blockIdx.x * ROWS;
    const int ty = threadIdx.x >> 6;    // 0..3
    const int col = threadIdx.x & 63;   // 0..63
    for (int i = threadIdx.x; i < ROWS * K; i += 256) {
        int r = i / K, c = i % K;
        int row = row0 + r;
        xs[r][c] = (row < N) ? in[(size_t)row * K + c] : 0.f;
    }
    __syncthreads();
    float a1[8], a2[8];
#pragma unroll
    for (int m = 0; m < 8; ++m) { a1[m] = 0.f; a2[m] = 0.f; }
#pragma unroll 4
    for (int k = 0; k < K; ++k) {
        float wa = Wa[k * 64 + col];
        float wb = Wb[k * 64 + col];
#pragma unroll
        for (int m = 0; m < 8; ++m) {
            float xv = xs[ty + m * 4][k];
            a1[m] = fmaf(xv, wa, a1[m]);
            a2[m] = fmaf(xv, wb, a2[m]);
        }
    }
#pragma unroll
    for (int m = 0; m < 8; ++m) {
        int row = row0 + ty + m * 4;
        if (row < N) {
            unsigned idx = ((unsigned)row << 6) + col;
            if (OUT1_BF) ((bf16*)out1v)[idx] = f2bf(a1[m]);
            else         ((float*)out1v)[idx] = a1[m];
            if (OUT2_BF) ((bf16*)out2v)[idx] = f2bf(a2[m]);
            else         ((float*)out2v)[idx] = a2[m];
        }
    }
}

// ---------------- CSR build step 1: integer degree count
__global__ __launch_bounds__(256) void deg_count_i(const int* __restrict__ dst,
                                                   int* __restrict__ degi, int E) {
    int e = blockIdx.x * blockDim.x + threadIdx.x;
    if (e < E) atomicAdd(&degi[dst[e]], 1);
}

// ---------------- CSR build step 2: exclusive scan over 50K degrees (single block)
__global__ __launch_bounds__(1024) void scan_offsets(const int* __restrict__ degi,
                                                     int* __restrict__ off,
                                                     int* __restrict__ cursor, int N) {
    __shared__ int part[1024];
    const int T = 1024;
    const int chunk = (N + T - 1) / T;
    const int t = threadIdx.x;
    const int lo = t * chunk;
    const int hi = min(lo + chunk, N);
    int s = 0;
    for (int i = lo; i < hi; ++i) s += degi[i];
    part[t] = s;
    __syncthreads();
    for (int d = 1; d < T; d <<= 1) {
        int u = (t >= d) ? part[t - d] : 0;
        __syncthreads();
        part[t] += u;
        __syncthreads();
    }
    int run = part[t] - s;
    for (int i = lo; i < hi; ++i) {
        off[i] = run;
        cursor[i] = run;
        run += degi[i];
    }
    if (t == T - 1) off[N] = part[T - 1];
}

// ---------------- CSR build step 3: place src ids
__global__ __launch_bounds__(256) void fill_csr(const int* __restrict__ src,
                                                const int* __restrict__ dst,
                                                int* __restrict__ cursor,
                                                int* __restrict__ csr, int E) {
    int e = blockIdx.x * blockDim.x + threadIdx.x;
    if (e < E) {
        int p = atomicAdd(&cursor[dst[e]], 1);
        csr[p] = src[e];
    }
}

// ---------------- gather + combine: h = ReLU(mean_{s in N(d)} y[s] + bias + r)
__global__ __launch_bounds__(256) void gather_combine(const bf16* __restrict__ y,
                                                      const float* __restrict__ r,
                                                      const int* __restrict__ csr,
                                                      const int* __restrict__ off,
                                                      const float* __restrict__ bias,
                                                      float* __restrict__ h, int N) {
    int t = blockIdx.x * blockDim.x + threadIdx.x;
    int node = t >> 6;
    if (node >= N) return;
    int j = t & 63;
    int s0 = off[node], s1 = off[node + 1];
    float acc = 0.f;
    int k = s0;
    for (; k + 3 < s1; k += 4) {
        int sa = csr[k], sb = csr[k + 1], sc = csr[k + 2], sd = csr[k + 3];
        float va = bf2f(y[((unsigned)sa << 6) + j]);
        float vb = bf2f(y[((unsigned)sb << 6) + j]);
        float vc = bf2f(y[((unsigned)sc << 6) + j]);
        float vd = bf2f(y[((unsigned)sd << 6) + j]);
        acc += (va + vb) + (vc + vd);
    }
    for (; k < s1; ++k)
        acc += bf2f(y[((unsigned)csr[k] << 6) + j]);
    float m = acc / fmaxf((float)(s1 - s0), 1.f);
    h[t] = fmaxf(m + bias[j] + r[t], 0.f);
}

// ---------------- fused edge stage: c = ea@Wbot+bm1 (LDS), then per-edge MLP
__global__ __launch_bounds__(256) void edge_fused(const bf16* __restrict__ aE,
                                                  const bf16* __restrict__ bE,
                                                  const float* __restrict__ ea,
                                                  const float* __restrict__ Wbot,
                                                  const float* __restrict__ bm1,
                                                  const float* __restrict__ wm2,
                                                  const float* __restrict__ bm2,
                                                  const int* __restrict__ src,
                                                  const int* __restrict__ dst,
                                                  float* __restrict__ out) {
    __shared__ float  ea_s[EBLK * 16];   // 8 KB
    __shared__ ushort c_s[EBLK * 64];    // 16 KB (bf16 bits)
    __shared__ int    sd_s[2 * EBLK];    // 1 KB
    const int t   = threadIdx.x;
    const int eb0 = blockIdx.x * EBLK;
    const int j   = t & 63;
    const int wv  = t >> 6;              // wave id 0..3

    // phase 0: coalesced staging
    for (int i = t; i < EBLK * 16; i += 256)
        ea_s[i] = ea[(size_t)eb0 * 16 + i];
    sd_s[t] = (t < EBLK) ? src[eb0 + t] : dst[eb0 + t - EBLK];

    float wcol[16];
#pragma unroll
    for (int k = 0; k < 16; ++k) wcol[k] = Wbot[k * 64 + j];
    const float bm1c = bm1[j];
    const float wm2c = wm2[j];
    const float bm2c = bm2[0];
    __syncthreads();

    // phase 1: c[e][j] = ea[e] . Wbot[:,j] + bm1[j]  (32 edges per thread)
#pragma unroll 4
    for (int i = 0; i < EBLK / 4; ++i) {
        int e = wv + i * 4;                              // wave-uniform
        const float4* er = (const float4*)(ea_s + e * 16);
        float4 e0 = er[0], e1 = er[1], e2 = er[2], e3 = er[3];
        float v = bm1c;
        v = fmaf(e0.x, wcol[0], v);  v = fmaf(e0.y, wcol[1], v);
        v = fmaf(e0.z, wcol[2], v);  v = fmaf(e0.w, wcol[3], v);
        v = fmaf(e1.x, wcol[4], v);  v = fmaf(e1.y, wcol[5], v);
        v = fmaf(e1.z, wcol[6], v);  v = fmaf(e1.w, wcol[7], v);
        v = fmaf(e2.x, wcol[8], v);  v = fmaf(e2.y, wcol[9], v);
        v = fmaf(e2.z, wcol[10], v); v = fmaf(e2.w, wcol[11], v);
        v = fmaf(e3.x, wcol[12], v); v = fmaf(e3.y, wcol[13], v);
        v = fmaf(e3.z, wcol[14], v); v = fmaf(e3.w, wcol[15], v);
        bf16 bv = f2bf(v);
        c_s[e * 64 + j] = *(ushort*)&bv;
    }
    __syncthreads();

    // phase 2: each wave finishes 32 edges (2 at a time)
    const int ebase = wv * 32;
    for (int i = 0; i < 32; i += 2) {
        int e0i = ebase + i, e1i = ebase + i + 1;
        int sa = sd_s[e0i], da = sd_s[EBLK + e0i];
        int sb = sd_s[e1i], db = sd_s[EBLK + e1i];
        ushort ca = c_s[e0i * 64 + j], cb = c_s[e1i * 64 + j];
        float va = bf2f(aE[((unsigned)sa << 6) + j]) +
                   bf2f(bE[((unsigned)da << 6) + j]) + bf2f(*(bf16*)&ca);
        float vb = bf2f(aE[((unsigned)sb << 6) + j]) +
                   bf2f(bE[((unsigned)db << 6) + j]) + bf2f(*(bf16*)&cb);
        float pa = fmaxf(va, 0.f) * wm2c;
        float pb = fmaxf(vb, 0.f) * wm2c;
#pragma unroll
        for (int o = 32; o; o >>= 1) {
            pa += __shfl_xor(pa, o, 64);
            pb += __shfl_xor(pb, o, 64);
        }
        float z = (j == 0) ? pa : pb;
        float r = 1.f / (1.f + __expf(-(z + bm2c)));
        if (j < 2) out[eb0 + e0i + j] = r;
    }
}

extern "C" void kernel_launch(void* const* d_in, const int* in_sizes, int n_in,
                              void* d_out, int out_size, void* d_ws, size_t ws_size,
                              hipStream_t stream) {
    const float* x         = (const float*)d_in[0];
    const float* edge_attr = (const float*)d_in[1];
    const float* W1l       = (const float*)d_in[2];
    const float* b1l       = (const float*)d_in[3];
    const float* W1r       = (const float*)d_in[4];
    const float* W2l       = (const float*)d_in[5];
    const float* b2l       = (const float*)d_in[6];
    const float* W2r       = (const float*)d_in[7];
    const float* Wm1       = (const float*)d_in[8];
    const float* bm1       = (const float*)d_in[9];
    const float* Wm2       = (const float*)d_in[10];
    const float* bm2       = (const float*)d_in[11];
    const int*   ei        = (const int*)d_in[12];   // [2, E] int32
    const int*   src       = ei;
    const int*   dst       = ei + N_EDGES;
    float* out = (float*)d_out;

    // workspace words: degi 50176 | off 50432 | cursor 50176 | csr 1.6M |
    //                  bfA 1.6M (bf16 x 3.2M) | bfB 1.6M | fR 3.2M | fH 3.2M
    int*   degi   = (int*)d_ws;
    int*   off    = degi + 50176;
    int*   cursor = off + 50432;
    int*   csr    = cursor + 50176;
    bf16*  bfA    = (bf16*)(csr + N_EDGES);          // y1 / y2 / aE (bf16)
    bf16*  bfB    = bfA + NODEF;                     // bE (bf16)
    float* fR     = (float*)(bfB + NODEF);           // r1 / r2 (f32)
    float* fH     = fR + NODEF;                      // h1 / h2 (f32)

    const int N = N_NODES, E = N_EDGES;
    const int egGrid = (E + 255) / 256;
    const int mmGrid = (N + 31) / 32;
    const int gcGrid = (N * 64 + 255) / 256;
    const int efGrid = E / EBLK;                     // 12500, exact

    // ---- CSR build (shared by both convs)
    hipMemsetAsync(degi, 0, N_NODES * sizeof(int), stream);
    deg_count_i<<<egGrid, 256, 0, stream>>>(dst, degi, E);
    scan_offsets<<<1, 1024, 0, stream>>>(degi, off, cursor, N);
    fill_csr<<<egGrid, 256, 0, stream>>>(src, dst, cursor, csr, E);

    // ---- conv1: y1(bf16) = x@W1l, r1(f32) = x@W1r
    dual_mm<128, true, false><<<mmGrid, 256, 0, stream>>>(x, W1l, W1r, bfA, fR, N);
    gather_combine<<<gcGrid, 256, 0, stream>>>(bfA, fR, csr, off, b1l, fH, N);   // h1

    // ---- conv2
    dual_mm<64, true, false><<<mmGrid, 256, 0, stream>>>(fH, W2l, W2r, bfA, fR, N);
    gather_combine<<<gcGrid, 256, 0, stream>>>(bfA, fR, csr, off, b2l, fH, N);   // h2

    // ---- edge precompute: aE(bf16) = h2 @ Wm1[0:64], bE(bf16) = h2 @ Wm1[64:128]
    dual_mm<64, true, true><<<mmGrid, 256, 0, stream>>>(fH, Wm1, Wm1 + 64 * 64, bfA, bfB, N);

    // ---- fused edge MLP
    edge_fused<<<efGrid, 256, 0, stream>>>(bfA, bfB, edge_attr, Wm1 + 128 * 64,
                                           bm1, Wm2, bm2, src, dst, out);
}

// Round 5
// 721.335 us; speedup vs baseline: 4.7525x; 1.0354x over previous
//
#include <hip/hip_runtime.h>
#include <hip/hip_bf16.h>
#include <math.h>

#define N_NODES 50000
#define N_EDGES 1600000
#define NODE_IN 128
#define HID 64
#define NODEF (N_NODES * HID)   // 3,200,000 elements per node buffer
#define EBLK 64                 // edges per block in edge_fused (E % EBLK == 0)

typedef __hip_bfloat16 bf16;

__device__ __forceinline__ float bf2f(bf16 v) { return __bfloat162float(v); }
__device__ __forceinline__ bf16 f2bf(float v) { return __float2bfloat16(v); }

// ---------------- dual GEMM: out1 = in @ Wa, out2 = in @ Wb ; in [N,K], W [K,64]
// 32 rows per block; each thread owns one output column for 8 rows.
template <int K, bool OUT1_BF, bool OUT2_BF>
__global__ __launch_bounds__(256) void dual_mm(const float* __restrict__ in,
                                               const float* __restrict__ Wa,
                                               const float* __restrict__ Wb,
                                               void* __restrict__ out1v,
                                               void* __restrict__ out2v, int N) {
    constexpr int ROWS = 32;
    __shared__ float xs[ROWS][K];
    const int row0 = blockIdx.x * ROWS;
    const int ty = threadIdx.x >> 6;    // 0..3
    const int col = threadIdx.x & 63;   // 0..63
    for (int i = threadIdx.x; i < ROWS * K; i += 256) {
        int r = i / K, c = i % K;
        int row = row0 + r;
        xs[r][c] = (row < N) ? in[(size_t)row * K + c] : 0.f;
    }
    __syncthreads();
    float a1[8], a2[8];
#pragma unroll
    for (int m = 0; m < 8; ++m) { a1[m] = 0.f; a2[m] = 0.f; }
#pragma unroll 4
    for (int k = 0; k < K; ++k) {
        float wa = Wa[k * 64 + col];
        float wb = Wb[k * 64 + col];
#pragma unroll
        for (int m = 0; m < 8; ++m) {
            float xv = xs[ty + m * 4][k];
            a1[m] = fmaf(xv, wa, a1[m]);
            a2[m] = fmaf(xv, wb, a2[m]);
        }
    }
#pragma unroll
    for (int m = 0; m < 8; ++m) {
        int row = row0 + ty + m * 4;
        if (row < N) {
            unsigned idx = ((unsigned)row << 6) + col;
            if (OUT1_BF) ((bf16*)out1v)[idx] = f2bf(a1[m]);
            else         ((float*)out1v)[idx] = a1[m];
            if (OUT2_BF) ((bf16*)out2v)[idx] = f2bf(a2[m]);
            else         ((float*)out2v)[idx] = a2[m];
        }
    }
}

// ---------------- CSR build step 1: integer degree count
__global__ __launch_bounds__(256) void deg_count_i(const int* __restrict__ dst,
                                                   int* __restrict__ degi, int E) {
    int e = blockIdx.x * blockDim.x + threadIdx.x;
    if (e < E) atomicAdd(&degi[dst[e]], 1);
}

// ---------------- CSR build step 2: exclusive scan over 50K degrees (single block)
__global__ __launch_bounds__(1024) void scan_offsets(const int* __restrict__ degi,
                                                     int* __restrict__ off,
                                                     int* __restrict__ cursor, int N) {
    __shared__ int part[1024];
    const int T = 1024;
    const int chunk = (N + T - 1) / T;
    const int t = threadIdx.x;
    const int lo = t * chunk;
    const int hi = min(lo + chunk, N);
    int s = 0;
    for (int i = lo; i < hi; ++i) s += degi[i];
    part[t] = s;
    __syncthreads();
    for (int d = 1; d < T; d <<= 1) {
        int u = (t >= d) ? part[t - d] : 0;
        __syncthreads();
        part[t] += u;
        __syncthreads();
    }
    int run = part[t] - s;
    for (int i = lo; i < hi; ++i) {
        off[i] = run;
        cursor[i] = run;
        run += degi[i];
    }
    if (t == T - 1) off[N] = part[T - 1];
}

// ---------------- CSR build step 3: place src ids
__global__ __launch_bounds__(256) void fill_csr(const int* __restrict__ src,
                                                const int* __restrict__ dst,
                                                int* __restrict__ cursor,
                                                int* __restrict__ csr, int E) {
    int e = blockIdx.x * blockDim.x + threadIdx.x;
    if (e < E) {
        int p = atomicAdd(&cursor[dst[e]], 1);
        csr[p] = src[e];
    }
}

// ---------------- gather + combine: h = ReLU(mean_{s in N(d)} y[s] + bias + r)
__global__ __launch_bounds__(256) void gather_combine(const bf16* __restrict__ y,
                                                      const float* __restrict__ r,
                                                      const int* __restrict__ csr,
                                                      const int* __restrict__ off,
                                                      const float* __restrict__ bias,
                                                      float* __restrict__ h, int N) {
    int t = blockIdx.x * blockDim.x + threadIdx.x;
    int node = t >> 6;
    if (node >= N) return;
    int j = t & 63;
    int s0 = off[node], s1 = off[node + 1];
    float acc = 0.f;
    int k = s0;
    for (; k + 7 < s1; k += 8) {
        int sidx[8];
#pragma unroll
        for (int u = 0; u < 8; ++u) sidx[u] = csr[k + u];
        float v[8];
#pragma unroll
        for (int u = 0; u < 8; ++u) v[u] = bf2f(y[((unsigned)sidx[u] << 6) + j]);
        acc += ((v[0] + v[1]) + (v[2] + v[3])) + ((v[4] + v[5]) + (v[6] + v[7]));
    }
    for (; k < s1; ++k)
        acc += bf2f(y[((unsigned)csr[k] << 6) + j]);
    float m = acc / fmaxf((float)(s1 - s0), 1.f);
    h[t] = fmaxf(m + bias[j] + r[t], 0.f);
}

// ---------------- fused edge stage: c = ea@Wbot+bm1 (LDS), then per-edge MLP
__global__ __launch_bounds__(256) void edge_fused(const bf16* __restrict__ aE,
                                                  const bf16* __restrict__ bE,
                                                  const float* __restrict__ ea,
                                                  const float* __restrict__ Wbot,
                                                  const float* __restrict__ bm1,
                                                  const float* __restrict__ wm2,
                                                  const float* __restrict__ bm2,
                                                  const int* __restrict__ src,
                                                  const int* __restrict__ dst,
                                                  float* __restrict__ out) {
    __shared__ float  ea_s[EBLK * 16];   // 4 KB
    __shared__ ushort c_s[EBLK * 64];    // 8 KB (bf16 bits)
    __shared__ int    sd_s[2 * EBLK];    // 0.5 KB
    const int t   = threadIdx.x;
    const int eb0 = blockIdx.x * EBLK;
    const int j   = t & 63;
    const int wv  = t >> 6;              // wave id 0..3

    // phase 0: coalesced staging
    for (int i = t; i < EBLK * 16; i += 256)
        ea_s[i] = ea[(size_t)eb0 * 16 + i];
    if (t < 2 * EBLK)
        sd_s[t] = (t < EBLK) ? src[eb0 + t] : dst[eb0 + t - EBLK];

    float wcol[16];
#pragma unroll
    for (int k = 0; k < 16; ++k) wcol[k] = Wbot[k * 64 + j];
    const float bm1c = bm1[j];
    const float wm2c = wm2[j];
    const float bm2c = bm2[0];
    __syncthreads();

    // phase 1: c[e][j] = ea[e] . Wbot[:,j] + bm1[j]  (16 edges per thread)
#pragma unroll 4
    for (int i = 0; i < EBLK / 4; ++i) {
        int e = wv + i * 4;                              // wave-uniform
        const float4* er = (const float4*)(ea_s + e * 16);
        float4 e0 = er[0], e1 = er[1], e2 = er[2], e3 = er[3];
        float v = bm1c;
        v = fmaf(e0.x, wcol[0], v);  v = fmaf(e0.y, wcol[1], v);
        v = fmaf(e0.z, wcol[2], v);  v = fmaf(e0.w, wcol[3], v);
        v = fmaf(e1.x, wcol[4], v);  v = fmaf(e1.y, wcol[5], v);
        v = fmaf(e1.z, wcol[6], v);  v = fmaf(e1.w, wcol[7], v);
        v = fmaf(e2.x, wcol[8], v);  v = fmaf(e2.y, wcol[9], v);
        v = fmaf(e2.z, wcol[10], v); v = fmaf(e2.w, wcol[11], v);
        v = fmaf(e3.x, wcol[12], v); v = fmaf(e3.y, wcol[13], v);
        v = fmaf(e3.z, wcol[14], v); v = fmaf(e3.w, wcol[15], v);
        bf16 bv = f2bf(v);
        c_s[e * 64 + j] = *(ushort*)&bv;
    }
    __syncthreads();

    // phase 2: each wave finishes 16 edges, 4 at a time (8 gathers in flight)
    const int ebase = wv * (EBLK / 4);
    for (int i = 0; i < EBLK / 4; i += 4) {
        int e0 = ebase + i, e1 = e0 + 1, e2 = e0 + 2, e3 = e0 + 3;
        int s0 = sd_s[e0], d0 = sd_s[EBLK + e0];
        int s1 = sd_s[e1], d1 = sd_s[EBLK + e1];
        int s2 = sd_s[e2], d2 = sd_s[EBLK + e2];
        int s3 = sd_s[e3], d3 = sd_s[EBLK + e3];
        float a0 = bf2f(aE[((unsigned)s0 << 6) + j]);
        float b0 = bf2f(bE[((unsigned)d0 << 6) + j]);
        float a1 = bf2f(aE[((unsigned)s1 << 6) + j]);
        float b1 = bf2f(bE[((unsigned)d1 << 6) + j]);
        float a2 = bf2f(aE[((unsigned)s2 << 6) + j]);
        float b2 = bf2f(bE[((unsigned)d2 << 6) + j]);
        float a3 = bf2f(aE[((unsigned)s3 << 6) + j]);
        float b3 = bf2f(bE[((unsigned)d3 << 6) + j]);
        ushort c0 = c_s[e0 * 64 + j], c1 = c_s[e1 * 64 + j];
        ushort c2 = c_s[e2 * 64 + j], c3 = c_s[e3 * 64 + j];
        float p0 = fmaxf(a0 + b0 + bf2f(*(bf16*)&c0), 0.f) * wm2c;
        float p1 = fmaxf(a1 + b1 + bf2f(*(bf16*)&c1), 0.f) * wm2c;
        float p2 = fmaxf(a2 + b2 + bf2f(*(bf16*)&c2), 0.f) * wm2c;
        float p3 = fmaxf(a3 + b3 + bf2f(*(bf16*)&c3), 0.f) * wm2c;
#pragma unroll
        for (int o = 32; o; o >>= 1) {
            p0 += __shfl_xor(p0, o, 64);
            p1 += __shfl_xor(p1, o, 64);
            p2 += __shfl_xor(p2, o, 64);
            p3 += __shfl_xor(p3, o, 64);
        }
        float z = (j == 0) ? p0 : (j == 1) ? p1 : (j == 2) ? p2 : p3;
        if (j < 4) out[eb0 + e0 + j] = 1.f / (1.f + __expf(-(z + bm2c)));
    }
}

extern "C" void kernel_launch(void* const* d_in, const int* in_sizes, int n_in,
                              void* d_out, int out_size, void* d_ws, size_t ws_size,
                              hipStream_t stream) {
    const float* x         = (const float*)d_in[0];
    const float* edge_attr = (const float*)d_in[1];
    const float* W1l       = (const float*)d_in[2];
    const float* b1l       = (const float*)d_in[3];
    const float* W1r       = (const float*)d_in[4];
    const float* W2l       = (const float*)d_in[5];
    const float* b2l       = (const float*)d_in[6];
    const float* W2r       = (const float*)d_in[7];
    const float* Wm1       = (const float*)d_in[8];
    const float* bm1       = (const float*)d_in[9];
    const float* Wm2       = (const float*)d_in[10];
    const float* bm2       = (const float*)d_in[11];
    const int*   ei        = (const int*)d_in[12];   // [2, E] int32
    const int*   src       = ei;
    const int*   dst       = ei + N_EDGES;
    float* out = (float*)d_out;

    // workspace words: degi 50176 | off 50432 | cursor 50176 | csr 1.6M |
    //                  bfA 1.6M (bf16 x 3.2M) | bfB 1.6M | fR 3.2M | fH 3.2M
    int*   degi   = (int*)d_ws;
    int*   off    = degi + 50176;
    int*   cursor = off + 50432;
    int*   csr    = cursor + 50176;
    bf16*  bfA    = (bf16*)(csr + N_EDGES);          // y1 / y2 / aE (bf16)
    bf16*  bfB    = bfA + NODEF;                     // bE (bf16)
    float* fR     = (float*)(bfB + NODEF);           // r1 / r2 (f32)
    float* fH     = fR + NODEF;                      // h1 / h2 (f32)

    const int N = N_NODES, E = N_EDGES;
    const int egGrid = (E + 255) / 256;
    const int mmGrid = (N + 31) / 32;
    const int gcGrid = (N * 64 + 255) / 256;
    const int efGrid = E / EBLK;                     // 25000, exact

    // ---- CSR build (shared by both convs)
    hipMemsetAsync(degi, 0, N_NODES * sizeof(int), stream);
    deg_count_i<<<egGrid, 256, 0, stream>>>(dst, degi, E);
    scan_offsets<<<1, 1024, 0, stream>>>(degi, off, cursor, N);
    fill_csr<<<egGrid, 256, 0, stream>>>(src, dst, cursor, csr, E);

    // ---- conv1: y1(bf16) = x@W1l, r1(f32) = x@W1r
    dual_mm<128, true, false><<<mmGrid, 256, 0, stream>>>(x, W1l, W1r, bfA, fR, N);
    gather_combine<<<gcGrid, 256, 0, stream>>>(bfA, fR, csr, off, b1l, fH, N);   // h1

    // ---- conv2
    dual_mm<64, true, false><<<mmGrid, 256, 0, stream>>>(fH, W2l, W2r, bfA, fR, N);
    gather_combine<<<gcGrid, 256, 0, stream>>>(bfA, fR, csr, off, b2l, fH, N);   // h2

    // ---- edge precompute: aE(bf16) = h2 @ Wm1[0:64], bE(bf16) = h2 @ Wm1[64:128]
    dual_mm<64, true, true><<<mmGrid, 256, 0, stream>>>(fH, Wm1, Wm1 + 64 * 64, bfA, bfB, N);

    // ---- fused edge MLP
    edge_fused<<<efGrid, 256, 0, stream>>>(bfA, bfB, edge_attr, Wm1 + 128 * 64,
                                           bm1, Wm2, bm2, src, dst, out);
}

// Round 6
// 551.554 us; speedup vs baseline: 6.2154x; 1.3078x over previous
//
#include <hip/hip_runtime.h>
#include <hip/hip_bf16.h>
#include <math.h>

#define N_NODES 50000
#define N_EDGES 1600000
#define NODE_IN 128
#define HID 64
#define NODEF (N_NODES * HID)   // 3,200,000 elements per node buffer
#define EBLK 64                 // edges per block in edge_fused (E % EBLK == 0)

typedef __hip_bfloat16 bf16;

__device__ __forceinline__ float bf2f(bf16 v) { return __bfloat162float(v); }
__device__ __forceinline__ bf16 f2bf(float v) { return __float2bfloat16(v); }

// ---------------- dual GEMM: out1 = in @ Wa, out2 = in @ Wb ; in [N,K], W [K,64]
// LDS holds x transposed (xs[k][row], pad 36) so each wave reads its 8 rows as
// two broadcast ds_read_b128 per k (vs 8 scalar ds_read_b32).
template <int K, bool OUT1_BF, bool OUT2_BF>
__global__ __launch_bounds__(256) void dual_mm(const float* __restrict__ in,
                                               const float* __restrict__ Wa,
                                               const float* __restrict__ Wb,
                                               void* __restrict__ out1v,
                                               void* __restrict__ out2v, int N) {
    constexpr int ROWS = 32;
    constexpr int PAD = 36;                 // words per k-slice: 16B-aligned
    __shared__ float xs[K * PAD];
    const int row0 = blockIdx.x * ROWS;
    const int ty = threadIdx.x >> 6;        // 0..3 -> rows ty*8..ty*8+7
    const int col = threadIdx.x & 63;
    for (int i = threadIdx.x; i < ROWS * K; i += 256) {
        int r = i / K, c = i % K;           // consecutive lanes: consecutive c
        int row = row0 + r;
        xs[c * PAD + r] = (row < N) ? in[(size_t)row * K + c] : 0.f;
    }
    __syncthreads();
    float a1[8], a2[8];
#pragma unroll
    for (int m = 0; m < 8; ++m) { a1[m] = 0.f; a2[m] = 0.f; }
#pragma unroll 4
    for (int k = 0; k < K; ++k) {
        const float4* xr = (const float4*)(xs + k * PAD + ty * 8);  // broadcast
        float4 xa = xr[0], xb = xr[1];
        float wa = Wa[k * 64 + col];
        float wb = Wb[k * 64 + col];
        a1[0] = fmaf(xa.x, wa, a1[0]); a2[0] = fmaf(xa.x, wb, a2[0]);
        a1[1] = fmaf(xa.y, wa, a1[1]); a2[1] = fmaf(xa.y, wb, a2[1]);
        a1[2] = fmaf(xa.z, wa, a1[2]); a2[2] = fmaf(xa.z, wb, a2[2]);
        a1[3] = fmaf(xa.w, wa, a1[3]); a2[3] = fmaf(xa.w, wb, a2[3]);
        a1[4] = fmaf(xb.x, wa, a1[4]); a2[4] = fmaf(xb.x, wb, a2[4]);
        a1[5] = fmaf(xb.y, wa, a1[5]); a2[5] = fmaf(xb.y, wb, a2[5]);
        a1[6] = fmaf(xb.z, wa, a1[6]); a2[6] = fmaf(xb.z, wb, a2[6]);
        a1[7] = fmaf(xb.w, wa, a1[7]); a2[7] = fmaf(xb.w, wb, a2[7]);
    }
#pragma unroll
    for (int m = 0; m < 8; ++m) {
        int row = row0 + ty * 8 + m;
        if (row < N) {
            unsigned idx = ((unsigned)row << 6) + col;
            if (OUT1_BF) ((bf16*)out1v)[idx] = f2bf(a1[m]);
            else         ((float*)out1v)[idx] = a1[m];
            if (OUT2_BF) ((bf16*)out2v)[idx] = f2bf(a2[m]);
            else         ((float*)out2v)[idx] = a2[m];
        }
    }
}

// ---------------- CSR build step 1: integer degree count
__global__ __launch_bounds__(256) void deg_count_i(const int* __restrict__ dst,
                                                   int* __restrict__ degi, int E) {
    int e = blockIdx.x * blockDim.x + threadIdx.x;
    if (e < E) atomicAdd(&degi[dst[e]], 1);
}

// ---------------- CSR build step 2: exclusive scan over 50K degrees (single block)
__global__ __launch_bounds__(1024) void scan_offsets(const int* __restrict__ degi,
                                                     int* __restrict__ off,
                                                     int* __restrict__ cursor, int N) {
    __shared__ int part[1024];
    const int T = 1024;
    const int chunk = (N + T - 1) / T;
    const int t = threadIdx.x;
    const int lo = t * chunk;
    const int hi = min(lo + chunk, N);
    int s = 0;
    for (int i = lo; i < hi; ++i) s += degi[i];
    part[t] = s;
    __syncthreads();
    for (int d = 1; d < T; d <<= 1) {
        int u = (t >= d) ? part[t - d] : 0;
        __syncthreads();
        part[t] += u;
        __syncthreads();
    }
    int run = part[t] - s;
    for (int i = lo; i < hi; ++i) {
        off[i] = run;
        cursor[i] = run;
        run += degi[i];
    }
    if (t == T - 1) off[N] = part[T - 1];
}

// ---------------- CSR build step 3: place src ids
__global__ __launch_bounds__(256) void fill_csr(const int* __restrict__ src,
                                                const int* __restrict__ dst,
                                                int* __restrict__ cursor,
                                                int* __restrict__ csr, int E) {
    int e = blockIdx.x * blockDim.x + threadIdx.x;
    if (e < E) {
        int p = atomicAdd(&cursor[dst[e]], 1);
        csr[p] = src[e];
    }
}

// ---------------- gather + combine: h = ReLU(mean_{s in N(d)} y[s] + bias + r)
__global__ __launch_bounds__(256) void gather_combine(const bf16* __restrict__ y,
                                                      const float* __restrict__ r,
                                                      const int* __restrict__ csr,
                                                      const int* __restrict__ off,
                                                      const float* __restrict__ bias,
                                                      float* __restrict__ h, int N) {
    int t = blockIdx.x * blockDim.x + threadIdx.x;
    int node = t >> 6;
    if (node >= N) return;
    int j = t & 63;
    int s0 = off[node], s1 = off[node + 1];
    float acc = 0.f;
    int k = s0;
    for (; k + 15 < s1; k += 16) {
        int sidx[16];
#pragma unroll
        for (int u = 0; u < 16; ++u) sidx[u] = csr[k + u];
        float v[16];
#pragma unroll
        for (int u = 0; u < 16; ++u) v[u] = bf2f(y[((unsigned)sidx[u] << 6) + j]);
        float s = 0.f;
#pragma unroll
        for (int u = 0; u < 16; ++u) s += v[u];
        acc += s;
    }
    for (; k + 3 < s1; k += 4) {
        int sa = csr[k], sb = csr[k + 1], sc = csr[k + 2], sd = csr[k + 3];
        float va = bf2f(y[((unsigned)sa << 6) + j]);
        float vb = bf2f(y[((unsigned)sb << 6) + j]);
        float vc = bf2f(y[((unsigned)sc << 6) + j]);
        float vd = bf2f(y[((unsigned)sd << 6) + j]);
        acc += (va + vb) + (vc + vd);
    }
    for (; k < s1; ++k)
        acc += bf2f(y[((unsigned)csr[k] << 6) + j]);
    float m = acc / fmaxf((float)(s1 - s0), 1.f);
    h[t] = fmaxf(m + bias[j] + r[t], 0.f);
}

// merge step for batched reduction: lanes with bit==0 keep/accumulate `lo`'s
// edge, lanes with bit==1 keep `hi`'s; partner lane supplies the other half.
__device__ __forceinline__ float merge_pair(float lo, float hi, int o, bool bit) {
    float keep = bit ? hi : lo;
    float send = bit ? lo : hi;
    return keep + __shfl_xor(send, o, 64);
}

// ---------------- fused edge stage: per-edge MLP, c computed inline
__global__ __launch_bounds__(256) void edge_fused(const bf16* __restrict__ aE,
                                                  const bf16* __restrict__ bE,
                                                  const float* __restrict__ ea,
                                                  const float* __restrict__ Wbot,
                                                  const float* __restrict__ bm1,
                                                  const float* __restrict__ wm2,
                                                  const float* __restrict__ bm2,
                                                  const int* __restrict__ src,
                                                  const int* __restrict__ dst,
                                                  float* __restrict__ out) {
    __shared__ float ea_s[EBLK * 16];    // 4 KB
    __shared__ int   sd_s[2 * EBLK];     // 0.5 KB
    const int t   = threadIdx.x;
    const int eb0 = blockIdx.x * EBLK;
    const int j   = t & 63;
    const int wv  = t >> 6;              // wave id 0..3

    // stage ea + indices (coalesced)
    for (int i = t; i < EBLK * 16; i += 256)
        ea_s[i] = ea[(size_t)eb0 * 16 + i];
    if (t < 2 * EBLK)
        sd_s[t] = (t < EBLK) ? src[eb0 + t] : dst[eb0 + t - EBLK];

    float wcol[16];
#pragma unroll
    for (int k = 0; k < 16; ++k) wcol[k] = Wbot[k * 64 + j];
    const float bm1c = bm1[j];
    const float wm2c = wm2[j];
    const float bm2c = bm2[0];
    const bool b5 = (j & 32) != 0, b4 = (j & 16) != 0, b3 = (j & 8) != 0;
    __syncthreads();

    const ushort* aU = (const ushort*)aE;
    const ushort* bU = (const ushort*)bE;

    // each wave: 16 edges in 2 groups of 8
    for (int g = 0; g < 2; ++g) {
        const int ebase = wv * 16 + g * 8;
        // 16 gathers in flight
        ushort av[8], bv[8];
#pragma unroll
        for (int u = 0; u < 8; ++u) {
            int e = ebase + u;
            int s = sd_s[e], d = sd_s[EBLK + e];
            av[u] = aU[((unsigned)s << 6) + j];
            bv[u] = bU[((unsigned)d << 6) + j];
        }
        // per-edge: c = ea.Wcol + bm1 (LDS broadcasts), add gathers, relu, *wm2
        float p[8];
#pragma unroll
        for (int u = 0; u < 8; ++u) {
            const float4* er = (const float4*)(ea_s + (ebase + u) * 16);
            float4 x0 = er[0], x1 = er[1], x2 = er[2], x3 = er[3];
            float v = bm1c;
            v = fmaf(x0.x, wcol[0], v);  v = fmaf(x0.y, wcol[1], v);
            v = fmaf(x0.z, wcol[2], v);  v = fmaf(x0.w, wcol[3], v);
            v = fmaf(x1.x, wcol[4], v);  v = fmaf(x1.y, wcol[5], v);
            v = fmaf(x1.z, wcol[6], v);  v = fmaf(x1.w, wcol[7], v);
            v = fmaf(x2.x, wcol[8], v);  v = fmaf(x2.y, wcol[9], v);
            v = fmaf(x2.z, wcol[10], v); v = fmaf(x2.w, wcol[11], v);
            v = fmaf(x3.x, wcol[12], v); v = fmaf(x3.y, wcol[13], v);
            v = fmaf(x3.z, wcol[14], v); v = fmaf(x3.w, wcol[15], v);
            bf16 ab = *(const bf16*)&av[u];
            bf16 bb = *(const bf16*)&bv[u];
            v += bf2f(ab) + bf2f(bb);
            p[u] = fmaxf(v, 0.f) * wm2c;
        }
        // batched reduction: 10 shfl for 8 edges
        float q0 = merge_pair(p[0], p[1], 32, b5);
        float q1 = merge_pair(p[2], p[3], 32, b5);
        float q2 = merge_pair(p[4], p[5], 32, b5);
        float q3 = merge_pair(p[6], p[7], 32, b5);
        float r0 = merge_pair(q0, q1, 16, b4);
        float r1 = merge_pair(q2, q3, 16, b4);
        float s  = merge_pair(r0, r1, 8, b3);
        s += __shfl_xor(s, 4, 64);
        s += __shfl_xor(s, 2, 64);
        s += __shfl_xor(s, 1, 64);
        // lane-group g8 = j>>3 holds edge 4*b3 + 2*b4 + b5
        if ((j & 7) == 0) {
            int m = 4 * ((j >> 3) & 1) + 2 * ((j >> 4) & 1) + ((j >> 5) & 1);
            out[eb0 + ebase + m] = 1.f / (1.f + __expf(-(s + bm2c)));
        }
    }
}

extern "C" void kernel_launch(void* const* d_in, const int* in_sizes, int n_in,
                              void* d_out, int out_size, void* d_ws, size_t ws_size,
                              hipStream_t stream) {
    const float* x         = (const float*)d_in[0];
    const float* edge_attr = (const float*)d_in[1];
    const float* W1l       = (const float*)d_in[2];
    const float* b1l       = (const float*)d_in[3];
    const float* W1r       = (const float*)d_in[4];
    const float* W2l       = (const float*)d_in[5];
    const float* b2l       = (const float*)d_in[6];
    const float* W2r       = (const float*)d_in[7];
    const float* Wm1       = (const float*)d_in[8];
    const float* bm1       = (const float*)d_in[9];
    const float* Wm2       = (const float*)d_in[10];
    const float* bm2       = (const float*)d_in[11];
    const int*   ei        = (const int*)d_in[12];   // [2, E] int32
    const int*   src       = ei;
    const int*   dst       = ei + N_EDGES;
    float* out = (float*)d_out;

    // workspace words: degi 50176 | off 50432 | cursor 50176 | csr 1.6M |
    //                  bfA 1.6M (bf16 x 3.2M) | bfB 1.6M | fR 3.2M | fH 3.2M
    int*   degi   = (int*)d_ws;
    int*   off    = degi + 50176;
    int*   cursor = off + 50432;
    int*   csr    = cursor + 50176;
    bf16*  bfA    = (bf16*)(csr + N_EDGES);          // y1 / y2 / aE (bf16)
    bf16*  bfB    = bfA + NODEF;                     // bE (bf16)
    float* fR     = (float*)(bfB + NODEF);           // r1 / r2 (f32)
    float* fH     = fR + NODEF;                      // h1 / h2 (f32)

    const int N = N_NODES, E = N_EDGES;
    const int egGrid = (E + 255) / 256;
    const int mmGrid = (N + 31) / 32;
    const int gcGrid = (N * 64 + 255) / 256;
    const int efGrid = E / EBLK;                     // 25000, exact

    // ---- CSR build (shared by both convs)
    hipMemsetAsync(degi, 0, N_NODES * sizeof(int), stream);
    deg_count_i<<<egGrid, 256, 0, stream>>>(dst, degi, E);
    scan_offsets<<<1, 1024, 0, stream>>>(degi, off, cursor, N);
    fill_csr<<<egGrid, 256, 0, stream>>>(src, dst, cursor, csr, E);

    // ---- conv1: y1(bf16) = x@W1l, r1(f32) = x@W1r
    dual_mm<128, true, false><<<mmGrid, 256, 0, stream>>>(x, W1l, W1r, bfA, fR, N);
    gather_combine<<<gcGrid, 256, 0, stream>>>(bfA, fR, csr, off, b1l, fH, N);   // h1

    // ---- conv2
    dual_mm<64, true, false><<<mmGrid, 256, 0, stream>>>(fH, W2l, W2r, bfA, fR, N);
    gather_combine<<<gcGrid, 256, 0, stream>>>(bfA, fR, csr, off, b2l, fH, N);   // h2

    // ---- edge precompute: aE(bf16) = h2 @ Wm1[0:64], bE(bf16) = h2 @ Wm1[64:128]
    dual_mm<64, true, true><<<mmGrid, 256, 0, stream>>>(fH, Wm1, Wm1 + 64 * 64, bfA, bfB, N);

    // ---- fused edge MLP
    edge_fused<<<efGrid, 256, 0, stream>>>(bfA, bfB, edge_attr, Wm1 + 128 * 64,
                                           bm1, Wm2, bm2, src, dst, out);
}

// Round 7
// 488.185 us; speedup vs baseline: 7.0222x; 1.1298x over previous
//
#include <hip/hip_runtime.h>
#include <hip/hip_bf16.h>
#include <math.h>

#define N_NODES 50000
#define N_EDGES 1600000
#define NODE_IN 128
#define HID 64
#define NODEF (N_NODES * HID)   // 3,200,000 elements per node buffer
#define EBLK 64                 // edges per block in edge_fused (E % EBLK == 0)
#define MM1_BLOCKS 1563         // ceil(50000/32)
#define DEG_BLOCKS 6250         // 1.6M / 256
#define NWIN 8                  // dst windows for fill_csr (50000/8 = 6250)

typedef __hip_bfloat16 bf16;

__device__ __forceinline__ float bf2f(bf16 v) { return __bfloat162float(v); }
__device__ __forceinline__ bf16 f2bf(float v) { return __float2bfloat16(v); }

// ---------------- dual GEMM: out1 = in @ Wa, out2 = in @ Wb ; in [N,K], W [K,64]
// LDS holds x transposed (xs[k][row], pad 36) so each wave reads its 8 rows as
// two broadcast ds_read_b128 per k.
template <int K, bool OUT1_BF, bool OUT2_BF>
__global__ __launch_bounds__(256) void dual_mm(const float* __restrict__ in,
                                               const float* __restrict__ Wa,
                                               const float* __restrict__ Wb,
                                               void* __restrict__ out1v,
                                               void* __restrict__ out2v, int N) {
    constexpr int ROWS = 32;
    constexpr int PAD = 36;
    __shared__ float xs[K * PAD];
    const int row0 = blockIdx.x * ROWS;
    const int ty = threadIdx.x >> 6;
    const int col = threadIdx.x & 63;
    for (int i = threadIdx.x; i < ROWS * K; i += 256) {
        int r = i / K, c = i % K;
        int row = row0 + r;
        xs[c * PAD + r] = (row < N) ? in[(size_t)row * K + c] : 0.f;
    }
    __syncthreads();
    float a1[8], a2[8];
#pragma unroll
    for (int m = 0; m < 8; ++m) { a1[m] = 0.f; a2[m] = 0.f; }
#pragma unroll 4
    for (int k = 0; k < K; ++k) {
        const float4* xr = (const float4*)(xs + k * PAD + ty * 8);
        float4 xa = xr[0], xb = xr[1];
        float wa = Wa[k * 64 + col];
        float wb = Wb[k * 64 + col];
        a1[0] = fmaf(xa.x, wa, a1[0]); a2[0] = fmaf(xa.x, wb, a2[0]);
        a1[1] = fmaf(xa.y, wa, a1[1]); a2[1] = fmaf(xa.y, wb, a2[1]);
        a1[2] = fmaf(xa.z, wa, a1[2]); a2[2] = fmaf(xa.z, wb, a2[2]);
        a1[3] = fmaf(xa.w, wa, a1[3]); a2[3] = fmaf(xa.w, wb, a2[3]);
        a1[4] = fmaf(xb.x, wa, a1[4]); a2[4] = fmaf(xb.x, wb, a2[4]);
        a1[5] = fmaf(xb.y, wa, a1[5]); a2[5] = fmaf(xb.y, wb, a2[5]);
        a1[6] = fmaf(xb.z, wa, a1[6]); a2[6] = fmaf(xb.z, wb, a2[6]);
        a1[7] = fmaf(xb.w, wa, a1[7]); a2[7] = fmaf(xb.w, wb, a2[7]);
    }
#pragma unroll
    for (int m = 0; m < 8; ++m) {
        int row = row0 + ty * 8 + m;
        if (row < N) {
            unsigned idx = ((unsigned)row << 6) + col;
            if (OUT1_BF) ((bf16*)out1v)[idx] = f2bf(a1[m]);
            else         ((float*)out1v)[idx] = a1[m];
            if (OUT2_BF) ((bf16*)out2v)[idx] = f2bf(a2[m]);
            else         ((float*)out2v)[idx] = a2[m];
        }
    }
}

// ---------------- fused conv1 GEMM + degree count (block-range split)
__global__ __launch_bounds__(256) void conv1_and_deg(const float* __restrict__ in,
                                                     const float* __restrict__ Wa,
                                                     const float* __restrict__ Wb,
                                                     bf16* __restrict__ out1,
                                                     float* __restrict__ out2,
                                                     const int* __restrict__ dst,
                                                     int* __restrict__ degi,
                                                     int N, int E) {
    constexpr int K = 128, ROWS = 32, PAD = 36;
    __shared__ float xs[K * PAD];
    const int bid = blockIdx.x;
    if (bid >= MM1_BLOCKS) {
        int e = (bid - MM1_BLOCKS) * 256 + threadIdx.x;
        if (e < E) atomicAdd(&degi[dst[e]], 1);
        return;
    }
    const int row0 = bid * ROWS;
    const int ty = threadIdx.x >> 6;
    const int col = threadIdx.x & 63;
    for (int i = threadIdx.x; i < ROWS * K; i += 256) {
        int r = i / K, c = i % K;
        int row = row0 + r;
        xs[c * PAD + r] = (row < N) ? in[(size_t)row * K + c] : 0.f;
    }
    __syncthreads();
    float a1[8], a2[8];
#pragma unroll
    for (int m = 0; m < 8; ++m) { a1[m] = 0.f; a2[m] = 0.f; }
#pragma unroll 4
    for (int k = 0; k < K; ++k) {
        const float4* xr = (const float4*)(xs + k * PAD + ty * 8);
        float4 xa = xr[0], xb = xr[1];
        float wa = Wa[k * 64 + col];
        float wb = Wb[k * 64 + col];
        a1[0] = fmaf(xa.x, wa, a1[0]); a2[0] = fmaf(xa.x, wb, a2[0]);
        a1[1] = fmaf(xa.y, wa, a1[1]); a2[1] = fmaf(xa.y, wb, a2[1]);
        a1[2] = fmaf(xa.z, wa, a1[2]); a2[2] = fmaf(xa.z, wb, a2[2]);
        a1[3] = fmaf(xa.w, wa, a1[3]); a2[3] = fmaf(xa.w, wb, a2[3]);
        a1[4] = fmaf(xb.x, wa, a1[4]); a2[4] = fmaf(xb.x, wb, a2[4]);
        a1[5] = fmaf(xb.y, wa, a1[5]); a2[5] = fmaf(xb.y, wb, a2[5]);
        a1[6] = fmaf(xb.z, wa, a1[6]); a2[6] = fmaf(xb.z, wb, a2[6]);
        a1[7] = fmaf(xb.w, wa, a1[7]); a2[7] = fmaf(xb.w, wb, a2[7]);
    }
#pragma unroll
    for (int m = 0; m < 8; ++m) {
        int row = row0 + ty * 8 + m;
        if (row < N) {
            unsigned idx = ((unsigned)row << 6) + col;
            out1[idx] = f2bf(a1[m]);
            out2[idx] = a2[m];
        }
    }
}

// ---------------- CSR build step 2: exclusive scan over 50K degrees (single block)
__global__ __launch_bounds__(1024) void scan_offsets(const int* __restrict__ degi,
                                                     int* __restrict__ off,
                                                     int* __restrict__ cursor, int N) {
    __shared__ int part[1024];
    const int T = 1024;
    const int chunk = (N + T - 1) / T;
    const int t = threadIdx.x;
    const int lo = t * chunk;
    const int hi = min(lo + chunk, N);
    int s = 0;
    for (int i = lo; i < hi; ++i) s += degi[i];
    part[t] = s;
    __syncthreads();
    for (int d = 1; d < T; d <<= 1) {
        int u = (t >= d) ? part[t - d] : 0;
        __syncthreads();
        part[t] += u;
        __syncthreads();
    }
    int run = part[t] - s;
    for (int i = lo; i < hi; ++i) {
        off[i] = run;
        cursor[i] = run;
        run += degi[i];
    }
    if (t == T - 1) off[N] = part[T - 1];
}

// ---------------- CSR build step 3: windowed scatter (pass-major grid).
// Window w covers dst in [w*6250, (w+1)*6250) -> csr stores stay in a ~0.8MB
// region while that window's blocks are resident => lines fill before eviction.
__global__ __launch_bounds__(256) void fill_csr_win(const int* __restrict__ src,
                                                    const int* __restrict__ dst,
                                                    int* __restrict__ cursor,
                                                    int* __restrict__ csr) {
    int w = blockIdx.x / DEG_BLOCKS;
    int chunk = blockIdx.x % DEG_BLOCKS;
    int e = chunk * 256 + threadIdx.x;
    int d = dst[e];
    int lo = w * (N_NODES / NWIN);
    int hi = lo + (N_NODES / NWIN);
    if (d >= lo && d < hi) {
        int p = atomicAdd(&cursor[d], 1);
        csr[p] = src[e];
    }
}

// ---------------- gather + combine: h = ReLU(mean_{s in N(d)} y[s] + bias + r)
__global__ __launch_bounds__(256) void gather_combine(const bf16* __restrict__ y,
                                                      const float* __restrict__ r,
                                                      const int* __restrict__ csr,
                                                      const int* __restrict__ off,
                                                      const float* __restrict__ bias,
                                                      float* __restrict__ h, int N) {
    int t = blockIdx.x * blockDim.x + threadIdx.x;
    int node = t >> 6;
    if (node >= N) return;
    int j = t & 63;
    int s0 = off[node], s1 = off[node + 1];
    float acc = 0.f;
    int k = s0;
    for (; k + 15 < s1; k += 16) {
        int sidx[16];
#pragma unroll
        for (int u = 0; u < 16; ++u) sidx[u] = csr[k + u];
        float v[16];
#pragma unroll
        for (int u = 0; u < 16; ++u) v[u] = bf2f(y[((unsigned)sidx[u] << 6) + j]);
        float s = 0.f;
#pragma unroll
        for (int u = 0; u < 16; ++u) s += v[u];
        acc += s;
    }
    for (; k + 3 < s1; k += 4) {
        int sa = csr[k], sb = csr[k + 1], sc = csr[k + 2], sd = csr[k + 3];
        float va = bf2f(y[((unsigned)sa << 6) + j]);
        float vb = bf2f(y[((unsigned)sb << 6) + j]);
        float vc = bf2f(y[((unsigned)sc << 6) + j]);
        float vd = bf2f(y[((unsigned)sd << 6) + j]);
        acc += (va + vb) + (vc + vd);
    }
    for (; k < s1; ++k)
        acc += bf2f(y[((unsigned)csr[k] << 6) + j]);
    float m = acc / fmaxf((float)(s1 - s0), 1.f);
    h[t] = fmaxf(m + bias[j] + r[t], 0.f);
}

// merge step for batched reduction
__device__ __forceinline__ float merge_pair(float lo, float hi, int o, bool bit) {
    float keep = bit ? hi : lo;
    float send = bit ? lo : hi;
    return keep + __shfl_xor(send, o, 64);
}

// ---------------- fused edge stage: per-edge MLP, c computed inline
__global__ __launch_bounds__(256) void edge_fused(const bf16* __restrict__ aE,
                                                  const bf16* __restrict__ bE,
                                                  const float* __restrict__ ea,
                                                  const float* __restrict__ Wbot,
                                                  const float* __restrict__ bm1,
                                                  const float* __restrict__ wm2,
                                                  const float* __restrict__ bm2,
                                                  const int* __restrict__ src,
                                                  const int* __restrict__ dst,
                                                  float* __restrict__ out) {
    __shared__ float ea_s[EBLK * 16];
    __shared__ int   sd_s[2 * EBLK];
    const int t   = threadIdx.x;
    const int eb0 = blockIdx.x * EBLK;
    const int j   = t & 63;
    const int wv  = t >> 6;

    for (int i = t; i < EBLK * 16; i += 256)
        ea_s[i] = ea[(size_t)eb0 * 16 + i];
    if (t < 2 * EBLK)
        sd_s[t] = (t < EBLK) ? src[eb0 + t] : dst[eb0 + t - EBLK];

    float wcol[16];
#pragma unroll
    for (int k = 0; k < 16; ++k) wcol[k] = Wbot[k * 64 + j];
    const float bm1c = bm1[j];
    const float wm2c = wm2[j];
    const float bm2c = bm2[0];
    const bool b5 = (j & 32) != 0, b4 = (j & 16) != 0, b3 = (j & 8) != 0;
    __syncthreads();

    const ushort* aU = (const ushort*)aE;
    const ushort* bU = (const ushort*)bE;

    for (int g = 0; g < 2; ++g) {
        const int ebase = wv * 16 + g * 8;
        ushort av[8], bv[8];
#pragma unroll
        for (int u = 0; u < 8; ++u) {
            int e = ebase + u;
            int s = sd_s[e], d = sd_s[EBLK + e];
            av[u] = aU[((unsigned)s << 6) + j];
            bv[u] = bU[((unsigned)d << 6) + j];
        }
        float p[8];
#pragma unroll
        for (int u = 0; u < 8; ++u) {
            const float4* er = (const float4*)(ea_s + (ebase + u) * 16);
            float4 x0 = er[0], x1 = er[1], x2 = er[2], x3 = er[3];
            float v = bm1c;
            v = fmaf(x0.x, wcol[0], v);  v = fmaf(x0.y, wcol[1], v);
            v = fmaf(x0.z, wcol[2], v);  v = fmaf(x0.w, wcol[3], v);
            v = fmaf(x1.x, wcol[4], v);  v = fmaf(x1.y, wcol[5], v);
            v = fmaf(x1.z, wcol[6], v);  v = fmaf(x1.w, wcol[7], v);
            v = fmaf(x2.x, wcol[8], v);  v = fmaf(x2.y, wcol[9], v);
            v = fmaf(x2.z, wcol[10], v); v = fmaf(x2.w, wcol[11], v);
            v = fmaf(x3.x, wcol[12], v); v = fmaf(x3.y, wcol[13], v);
            v = fmaf(x3.z, wcol[14], v); v = fmaf(x3.w, wcol[15], v);
            bf16 ab = *(const bf16*)&av[u];
            bf16 bb = *(const bf16*)&bv[u];
            v += bf2f(ab) + bf2f(bb);
            p[u] = fmaxf(v, 0.f) * wm2c;
        }
        float q0 = merge_pair(p[0], p[1], 32, b5);
        float q1 = merge_pair(p[2], p[3], 32, b5);
        float q2 = merge_pair(p[4], p[5], 32, b5);
        float q3 = merge_pair(p[6], p[7], 32, b5);
        float r0 = merge_pair(q0, q1, 16, b4);
        float r1 = merge_pair(q2, q3, 16, b4);
        float s  = merge_pair(r0, r1, 8, b3);
        s += __shfl_xor(s, 4, 64);
        s += __shfl_xor(s, 2, 64);
        s += __shfl_xor(s, 1, 64);
        if ((j & 7) == 0) {
            int m = 4 * ((j >> 3) & 1) + 2 * ((j >> 4) & 1) + ((j >> 5) & 1);
            out[eb0 + ebase + m] = 1.f / (1.f + __expf(-(s + bm2c)));
        }
    }
}

extern "C" void kernel_launch(void* const* d_in, const int* in_sizes, int n_in,
                              void* d_out, int out_size, void* d_ws, size_t ws_size,
                              hipStream_t stream) {
    const float* x         = (const float*)d_in[0];
    const float* edge_attr = (const float*)d_in[1];
    const float* W1l       = (const float*)d_in[2];
    const float* b1l       = (const float*)d_in[3];
    const float* W1r       = (const float*)d_in[4];
    const float* W2l       = (const float*)d_in[5];
    const float* b2l       = (const float*)d_in[6];
    const float* W2r       = (const float*)d_in[7];
    const float* Wm1       = (const float*)d_in[8];
    const float* bm1       = (const float*)d_in[9];
    const float* Wm2       = (const float*)d_in[10];
    const float* bm2       = (const float*)d_in[11];
    const int*   ei        = (const int*)d_in[12];   // [2, E] int32
    const int*   src       = ei;
    const int*   dst       = ei + N_EDGES;
    float* out = (float*)d_out;

    int*   degi   = (int*)d_ws;
    int*   off    = degi + 50176;
    int*   cursor = off + 50432;
    int*   csr    = cursor + 50176;
    bf16*  bfA    = (bf16*)(csr + N_EDGES);          // y1 / y2 / aE (bf16)
    bf16*  bfB    = bfA + NODEF;                     // bE (bf16)
    float* fR     = (float*)(bfB + NODEF);           // r1 / r2 (f32)
    float* fH     = fR + NODEF;                      // h1 / h2 (f32)

    const int N = N_NODES, E = N_EDGES;
    const int mmGrid = (N + 31) / 32;                // 1563 == MM1_BLOCKS
    const int gcGrid = (N * 64 + 255) / 256;
    const int efGrid = E / EBLK;

    // ---- conv1 GEMM + degree count fused (deg hides under GEMM)
    hipMemsetAsync(degi, 0, N_NODES * sizeof(int), stream);
    conv1_and_deg<<<MM1_BLOCKS + DEG_BLOCKS, 256, 0, stream>>>(
        x, W1l, W1r, bfA, fR, dst, degi, N, E);
    scan_offsets<<<1, 1024, 0, stream>>>(degi, off, cursor, N);
    fill_csr_win<<<NWIN * DEG_BLOCKS, 256, 0, stream>>>(src, dst, cursor, csr);

    // ---- conv1 aggregate
    gather_combine<<<gcGrid, 256, 0, stream>>>(bfA, fR, csr, off, b1l, fH, N);   // h1

    // ---- conv2
    dual_mm<64, true, false><<<mmGrid, 256, 0, stream>>>(fH, W2l, W2r, bfA, fR, N);
    gather_combine<<<gcGrid, 256, 0, stream>>>(bfA, fR, csr, off, b2l, fH, N);   // h2

    // ---- edge precompute: aE(bf16) = h2 @ Wm1[0:64], bE(bf16) = h2 @ Wm1[64:128]
    dual_mm<64, true, true><<<mmGrid, 256, 0, stream>>>(fH, Wm1, Wm1 + 64 * 64, bfA, bfB, N);

    // ---- fused edge MLP
    edge_fused<<<efGrid, 256, 0, stream>>>(bfA, bfB, edge_attr, Wm1 + 128 * 64,
                                           bm1, Wm2, bm2, src, dst, out);
}

// Round 8
// 469.211 us; speedup vs baseline: 7.3061x; 1.0404x over previous
//
#include <hip/hip_runtime.h>
#include <hip/hip_bf16.h>
#include <math.h>

#define N_NODES 50000
#define N_EDGES 1600000
#define NODE_IN 128
#define HID 64
#define NODEF (N_NODES * HID)   // 3,200,000 elements per node buffer
#define EBLK 64                 // edges per block in edge_fused (E % EBLK == 0)
#define MM1_BLOCKS 1563         // ceil(50000/32)
#define DEG_BLOCKS 6250         // 1.6M / 256
#define NWIN 8                  // dst windows for fill_csr (50000/8 = 6250)

typedef __hip_bfloat16 bf16;
typedef _Float16 half2t __attribute__((ext_vector_type(2)));

__device__ __forceinline__ float bf2f(bf16 v) { return __bfloat162float(v); }
__device__ __forceinline__ bf16 f2bf(float v) { return __float2bfloat16(v); }

// ---------------- fused conv1 GEMM + degree count (block-range split)
__global__ __launch_bounds__(256) void conv1_and_deg(const float* __restrict__ in,
                                                     const float* __restrict__ Wa,
                                                     const float* __restrict__ Wb,
                                                     bf16* __restrict__ out1,
                                                     float* __restrict__ out2,
                                                     const int* __restrict__ dst,
                                                     int* __restrict__ degi,
                                                     int N, int E) {
    constexpr int K = 128, ROWS = 32, PAD = 36;
    __shared__ float xs[K * PAD];
    const int bid = blockIdx.x;
    if (bid >= MM1_BLOCKS) {
        int e = (bid - MM1_BLOCKS) * 256 + threadIdx.x;
        if (e < E) atomicAdd(&degi[dst[e]], 1);
        return;
    }
    const int row0 = bid * ROWS;
    const int ty = threadIdx.x >> 6;
    const int col = threadIdx.x & 63;
    for (int i = threadIdx.x; i < ROWS * K; i += 256) {
        int r = i / K, c = i % K;
        int row = row0 + r;
        xs[c * PAD + r] = (row < N) ? in[(size_t)row * K + c] : 0.f;
    }
    __syncthreads();
    float a1[8], a2[8];
#pragma unroll
    for (int m = 0; m < 8; ++m) { a1[m] = 0.f; a2[m] = 0.f; }
#pragma unroll 4
    for (int k = 0; k < K; ++k) {
        const float4* xr = (const float4*)(xs + k * PAD + ty * 8);
        float4 xa = xr[0], xb = xr[1];
        float wa = Wa[k * 64 + col];
        float wb = Wb[k * 64 + col];
        a1[0] = fmaf(xa.x, wa, a1[0]); a2[0] = fmaf(xa.x, wb, a2[0]);
        a1[1] = fmaf(xa.y, wa, a1[1]); a2[1] = fmaf(xa.y, wb, a2[1]);
        a1[2] = fmaf(xa.z, wa, a1[2]); a2[2] = fmaf(xa.z, wb, a2[2]);
        a1[3] = fmaf(xa.w, wa, a1[3]); a2[3] = fmaf(xa.w, wb, a2[3]);
        a1[4] = fmaf(xb.x, wa, a1[4]); a2[4] = fmaf(xb.x, wb, a2[4]);
        a1[5] = fmaf(xb.y, wa, a1[5]); a2[5] = fmaf(xb.y, wb, a2[5]);
        a1[6] = fmaf(xb.z, wa, a1[6]); a2[6] = fmaf(xb.z, wb, a2[6]);
        a1[7] = fmaf(xb.w, wa, a1[7]); a2[7] = fmaf(xb.w, wb, a2[7]);
    }
#pragma unroll
    for (int m = 0; m < 8; ++m) {
        int row = row0 + ty * 8 + m;
        if (row < N) {
            unsigned idx = ((unsigned)row << 6) + col;
            out1[idx] = f2bf(a1[m]);
            out2[idx] = a2[m];
        }
    }
}

// ---------------- CSR build step 2: exclusive scan over 50K degrees (single block)
__global__ __launch_bounds__(1024) void scan_offsets(const int* __restrict__ degi,
                                                     int* __restrict__ off,
                                                     int* __restrict__ cursor, int N) {
    __shared__ int part[1024];
    const int T = 1024;
    const int chunk = (N + T - 1) / T;
    const int t = threadIdx.x;
    const int lo = t * chunk;
    const int hi = min(lo + chunk, N);
    int s = 0;
    for (int i = lo; i < hi; ++i) s += degi[i];
    part[t] = s;
    __syncthreads();
    for (int d = 1; d < T; d <<= 1) {
        int u = (t >= d) ? part[t - d] : 0;
        __syncthreads();
        part[t] += u;
        __syncthreads();
    }
    int run = part[t] - s;
    for (int i = lo; i < hi; ++i) {
        off[i] = run;
        cursor[i] = run;
        run += degi[i];
    }
    if (t == T - 1) off[N] = part[T - 1];
}

// ---------------- CSR build step 3: windowed scatter (pass-major grid)
__global__ __launch_bounds__(256) void fill_csr_win(const int* __restrict__ src,
                                                    const int* __restrict__ dst,
                                                    int* __restrict__ cursor,
                                                    int* __restrict__ csr) {
    int w = blockIdx.x / DEG_BLOCKS;
    int chunk = blockIdx.x % DEG_BLOCKS;
    int e = chunk * 256 + threadIdx.x;
    int d = dst[e];
    int lo = w * (N_NODES / NWIN);
    int hi = lo + (N_NODES / NWIN);
    if (d >= lo && d < hi) {
        int p = atomicAdd(&cursor[d], 1);
        csr[p] = src[e];
    }
}

// ---------------- fused gather + dual GEMM: per 32-node block,
//   h = ReLU(mean_{s in N(d)} y[s] + bias + r)  (into LDS, transposed)
//   out1 = h @ Wa, out2 = h @ Wb
template <bool OUT1_BF, bool OUT2_BF>
__global__ __launch_bounds__(256) void gather_mm(const bf16* __restrict__ y,
                                                 const float* __restrict__ r,
                                                 const int* __restrict__ csr,
                                                 const int* __restrict__ off,
                                                 const float* __restrict__ bias,
                                                 const float* __restrict__ Wa,
                                                 const float* __restrict__ Wb,
                                                 void* __restrict__ out1v,
                                                 void* __restrict__ out2v, int N) {
    constexpr int K = 64, ROWS = 32, PAD = 36;
    __shared__ float xs[K * PAD];
    const int row0 = blockIdx.x * ROWS;
    const int j  = threadIdx.x & 63;
    const int wv = threadIdx.x >> 6;
    const float bj = bias[j];

    // ---- gather phase: wave wv produces rows wv*8 .. wv*8+7
    for (int m = 0; m < 8; ++m) {
        int lr = wv * 8 + m;
        int node = row0 + lr;
        float val = 0.f;
        if (node < N) {
            int s0 = off[node], s1 = off[node + 1];
            float acc = 0.f;
            int k = s0;
            for (; k + 15 < s1; k += 16) {
                int sidx[16];
#pragma unroll
                for (int u = 0; u < 16; ++u) sidx[u] = csr[k + u];
                float v[16];
#pragma unroll
                for (int u = 0; u < 16; ++u) v[u] = bf2f(y[((unsigned)sidx[u] << 6) + j]);
                float s = 0.f;
#pragma unroll
                for (int u = 0; u < 16; ++u) s += v[u];
                acc += s;
            }
            for (; k + 3 < s1; k += 4) {
                int sa = csr[k], sb = csr[k + 1], sc = csr[k + 2], sd = csr[k + 3];
                float va = bf2f(y[((unsigned)sa << 6) + j]);
                float vb = bf2f(y[((unsigned)sb << 6) + j]);
                float vc = bf2f(y[((unsigned)sc << 6) + j]);
                float vd = bf2f(y[((unsigned)sd << 6) + j]);
                acc += (va + vb) + (vc + vd);
            }
            for (; k < s1; ++k)
                acc += bf2f(y[((unsigned)csr[k] << 6) + j]);
            float mean = acc / fmaxf((float)(s1 - s0), 1.f);
            val = fmaxf(mean + bj + r[((unsigned)node << 6) + j], 0.f);
        }
        xs[j * PAD + lr] = val;     // transposed for GEMM
    }
    __syncthreads();

    // ---- GEMM phase (identical structure to dual_mm<64>)
    float a1[8], a2[8];
#pragma unroll
    for (int m = 0; m < 8; ++m) { a1[m] = 0.f; a2[m] = 0.f; }
#pragma unroll 4
    for (int k = 0; k < K; ++k) {
        const float4* xr = (const float4*)(xs + k * PAD + wv * 8);
        float4 xa = xr[0], xb = xr[1];
        float wa = Wa[k * 64 + j];
        float wb = Wb[k * 64 + j];
        a1[0] = fmaf(xa.x, wa, a1[0]); a2[0] = fmaf(xa.x, wb, a2[0]);
        a1[1] = fmaf(xa.y, wa, a1[1]); a2[1] = fmaf(xa.y, wb, a2[1]);
        a1[2] = fmaf(xa.z, wa, a1[2]); a2[2] = fmaf(xa.z, wb, a2[2]);
        a1[3] = fmaf(xa.w, wa, a1[3]); a2[3] = fmaf(xa.w, wb, a2[3]);
        a1[4] = fmaf(xb.x, wa, a1[4]); a2[4] = fmaf(xb.x, wb, a2[4]);
        a1[5] = fmaf(xb.y, wa, a1[5]); a2[5] = fmaf(xb.y, wb, a2[5]);
        a1[6] = fmaf(xb.z, wa, a1[6]); a2[6] = fmaf(xb.z, wb, a2[6]);
        a1[7] = fmaf(xb.w, wa, a1[7]); a2[7] = fmaf(xb.w, wb, a2[7]);
    }
#pragma unroll
    for (int m = 0; m < 8; ++m) {
        int row = row0 + wv * 8 + m;
        if (row < N) {
            unsigned idx = ((unsigned)row << 6) + j;
            if (OUT1_BF) ((bf16*)out1v)[idx] = f2bf(a1[m]);
            else         ((float*)out1v)[idx] = a1[m];
            if (OUT2_BF) ((bf16*)out2v)[idx] = f2bf(a2[m]);
            else         ((float*)out2v)[idx] = a2[m];
        }
    }
}

// merge step for batched reduction
__device__ __forceinline__ float merge_pair(float lo, float hi, int o, bool bit) {
    float keep = bit ? hi : lo;
    float send = bit ? lo : hi;
    return keep + __shfl_xor(send, o, 64);
}

// ---------------- fused edge stage: per-edge MLP, ea-projection via v_dot2_f32_f16
__global__ __launch_bounds__(256) void edge_fused(const bf16* __restrict__ aE,
                                                  const bf16* __restrict__ bE,
                                                  const float* __restrict__ ea,
                                                  const float* __restrict__ Wbot,
                                                  const float* __restrict__ bm1,
                                                  const float* __restrict__ wm2,
                                                  const float* __restrict__ bm2,
                                                  const int* __restrict__ src,
                                                  const int* __restrict__ dst,
                                                  float* __restrict__ out) {
    __shared__ unsigned ea_s[EBLK * 8];  // ea rows packed as half2 (2 KB)
    __shared__ int      sd_s[2 * EBLK];
    const int t   = threadIdx.x;
    const int eb0 = blockIdx.x * EBLK;
    const int j   = t & 63;
    const int wv  = t >> 6;

    {   // stage ea -> f16 pairs (coalesced float2 reads)
        const float2* eaf2 = (const float2*)(ea + (size_t)eb0 * 16);
        for (int i = t; i < EBLK * 8; i += 256) {
            float2 f = eaf2[i];
            half2t p;
            p.x = (_Float16)f.x;
            p.y = (_Float16)f.y;
            ea_s[i] = __builtin_bit_cast(unsigned, p);
        }
    }
    if (t < 2 * EBLK)
        sd_s[t] = (t < EBLK) ? src[eb0 + t] : dst[eb0 + t - EBLK];

    half2t wh[8];
#pragma unroll
    for (int kk = 0; kk < 8; ++kk) {
        wh[kk].x = (_Float16)Wbot[(2 * kk) * 64 + j];
        wh[kk].y = (_Float16)Wbot[(2 * kk + 1) * 64 + j];
    }
    const float bm1c = bm1[j];
    const float wm2c = wm2[j];
    const float bm2c = bm2[0];
    const bool b5 = (j & 32) != 0, b4 = (j & 16) != 0, b3 = (j & 8) != 0;
    __syncthreads();

    const ushort* aU = (const ushort*)aE;
    const ushort* bU = (const ushort*)bE;

    for (int g = 0; g < 2; ++g) {
        const int ebase = wv * 16 + g * 8;
        ushort av[8], bv[8];
#pragma unroll
        for (int u = 0; u < 8; ++u) {
            int e = ebase + u;
            av[u] = aU[((unsigned)sd_s[e] << 6) + j];
            bv[u] = bU[((unsigned)sd_s[EBLK + e] << 6) + j];
        }
        float p[8];
#pragma unroll
        for (int u = 0; u < 8; ++u) {
            const uint4* er = (const uint4*)(ea_s + (ebase + u) * 8);
            uint4 qa = er[0], qb = er[1];
            float v = bm1c;
            v = __builtin_amdgcn_fdot2(__builtin_bit_cast(half2t, qa.x), wh[0], v, false);
            v = __builtin_amdgcn_fdot2(__builtin_bit_cast(half2t, qa.y), wh[1], v, false);
            v = __builtin_amdgcn_fdot2(__builtin_bit_cast(half2t, qa.z), wh[2], v, false);
            v = __builtin_amdgcn_fdot2(__builtin_bit_cast(half2t, qa.w), wh[3], v, false);
            v = __builtin_amdgcn_fdot2(__builtin_bit_cast(half2t, qb.x), wh[4], v, false);
            v = __builtin_amdgcn_fdot2(__builtin_bit_cast(half2t, qb.y), wh[5], v, false);
            v = __builtin_amdgcn_fdot2(__builtin_bit_cast(half2t, qb.z), wh[6], v, false);
            v = __builtin_amdgcn_fdot2(__builtin_bit_cast(half2t, qb.w), wh[7], v, false);
            bf16 ab = *(const bf16*)&av[u];
            bf16 bb = *(const bf16*)&bv[u];
            v += bf2f(ab) + bf2f(bb);
            p[u] = fmaxf(v, 0.f) * wm2c;
        }
        float q0 = merge_pair(p[0], p[1], 32, b5);
        float q1 = merge_pair(p[2], p[3], 32, b5);
        float q2 = merge_pair(p[4], p[5], 32, b5);
        float q3 = merge_pair(p[6], p[7], 32, b5);
        float r0 = merge_pair(q0, q1, 16, b4);
        float r1 = merge_pair(q2, q3, 16, b4);
        float s  = merge_pair(r0, r1, 8, b3);
        s += __shfl_xor(s, 4, 64);
        s += __shfl_xor(s, 2, 64);
        s += __shfl_xor(s, 1, 64);
        if ((j & 7) == 0) {
            int m = 4 * ((j >> 3) & 1) + 2 * ((j >> 4) & 1) + ((j >> 5) & 1);
            out[eb0 + ebase + m] = 1.f / (1.f + __expf(-(s + bm2c)));
        }
    }
}

extern "C" void kernel_launch(void* const* d_in, const int* in_sizes, int n_in,
                              void* d_out, int out_size, void* d_ws, size_t ws_size,
                              hipStream_t stream) {
    const float* x         = (const float*)d_in[0];
    const float* edge_attr = (const float*)d_in[1];
    const float* W1l       = (const float*)d_in[2];
    const float* b1l       = (const float*)d_in[3];
    const float* W1r       = (const float*)d_in[4];
    const float* W2l       = (const float*)d_in[5];
    const float* b2l       = (const float*)d_in[6];
    const float* W2r       = (const float*)d_in[7];
    const float* Wm1       = (const float*)d_in[8];
    const float* bm1       = (const float*)d_in[9];
    const float* Wm2       = (const float*)d_in[10];
    const float* bm2       = (const float*)d_in[11];
    const int*   ei        = (const int*)d_in[12];   // [2, E] int32
    const int*   src       = ei;
    const int*   dst       = ei + N_EDGES;
    float* out = (float*)d_out;

    // workspace words: degi 50176 | off 50432 | cursor 50176 | csr 1.6M |
    //                  bfA/bfB/bfC (bf16 x 3.2M = 1.6M words each) | fR 3.2M | fR2 3.2M
    int*   degi   = (int*)d_ws;
    int*   off    = degi + 50176;
    int*   cursor = off + 50432;
    int*   csr    = cursor + 50176;
    bf16*  bfA    = (bf16*)(csr + N_EDGES);  // y1 / aE
    bf16*  bfB    = bfA + NODEF;             // y2
    bf16*  bfC    = bfB + NODEF;             // bE
    float* fR     = (float*)(bfC + NODEF);   // r1
    float* fR2    = fR + NODEF;              // r2

    const int N = N_NODES, E = N_EDGES;
    const int mmGrid = (N + 31) / 32;        // 1563 == MM1_BLOCKS
    const int efGrid = E / EBLK;

    // ---- conv1 GEMM + degree count fused (deg hides under GEMM)
    hipMemsetAsync(degi, 0, N_NODES * sizeof(int), stream);
    conv1_and_deg<<<MM1_BLOCKS + DEG_BLOCKS, 256, 0, stream>>>(
        x, W1l, W1r, bfA, fR, dst, degi, N, E);
    scan_offsets<<<1, 1024, 0, stream>>>(degi, off, cursor, N);
    fill_csr_win<<<NWIN * DEG_BLOCKS, 256, 0, stream>>>(src, dst, cursor, csr);

    // ---- conv2: gather h1 (from y1,r1) fused with y2 = h1@W2l, r2 = h1@W2r
    gather_mm<true, false><<<mmGrid, 256, 0, stream>>>(
        bfA, fR, csr, off, b1l, W2l, W2r, bfB, fR2, N);

    // ---- edge precompute: gather h2 (from y2,r2) fused with aE/bE = h2@Wm1 halves
    gather_mm<true, true><<<mmGrid, 256, 0, stream>>>(
        bfB, fR2, csr, off, b2l, Wm1, Wm1 + 64 * 64, bfA, bfC, N);

    // ---- fused edge MLP
    edge_fused<<<efGrid, 256, 0, stream>>>(bfA, bfC, edge_attr, Wm1 + 128 * 64,
                                           bm1, Wm2, bm2, src, dst, out);
}

// Round 9
// 369.575 us; speedup vs baseline: 9.2758x; 1.2696x over previous
//
#include <hip/hip_runtime.h>
#include <hip/hip_bf16.h>
#include <math.h>

#define N_NODES 50000
#define N_EDGES 1600000
#define NODE_IN 128
#define HID 64
#define NODEF (N_NODES * HID)   // 3,200,000 elements per node buffer
#define EBLK 64                 // edges per block in edge_fused (E % EBLK == 0)
#define MM1_BLOCKS 1563         // ceil(50000/32)
#define DEG_BLOCKS 6250         // 1.6M / 256
#define NWIN 8                  // dst windows for fill_csr (50000/8 = 6250)
#define SCAN_BLOCKS 49          // ceil(50000/1024)

typedef __hip_bfloat16 bf16;
typedef _Float16 half2t __attribute__((ext_vector_type(2)));

__device__ __forceinline__ float bf2f(bf16 v) { return __bfloat162float(v); }
__device__ __forceinline__ bf16 f2bf(float v) { return __float2bfloat16(v); }

// ---------------- fused conv1 GEMM + degree count (block-range split)
__global__ __launch_bounds__(256) void conv1_and_deg(const float* __restrict__ in,
                                                     const float* __restrict__ Wa,
                                                     const float* __restrict__ Wb,
                                                     bf16* __restrict__ out1,
                                                     float* __restrict__ out2,
                                                     const int* __restrict__ dst,
                                                     int* __restrict__ degi,
                                                     int N, int E) {
    constexpr int K = 128, ROWS = 32, PAD = 36;
    __shared__ float xs[K * PAD];
    const int bid = blockIdx.x;
    if (bid >= MM1_BLOCKS) {
        int e = (bid - MM1_BLOCKS) * 256 + threadIdx.x;
        if (e < E) atomicAdd(&degi[dst[e]], 1);
        return;
    }
    const int row0 = bid * ROWS;
    const int ty = threadIdx.x >> 6;
    const int col = threadIdx.x & 63;
    for (int i = threadIdx.x; i < ROWS * K; i += 256) {
        int r = i / K, c = i % K;
        int row = row0 + r;
        xs[c * PAD + r] = (row < N) ? in[(size_t)row * K + c] : 0.f;
    }
    __syncthreads();
    float a1[8], a2[8];
#pragma unroll
    for (int m = 0; m < 8; ++m) { a1[m] = 0.f; a2[m] = 0.f; }
#pragma unroll 4
    for (int k = 0; k < K; ++k) {
        const float4* xr = (const float4*)(xs + k * PAD + ty * 8);
        float4 xa = xr[0], xb = xr[1];
        float wa = Wa[k * 64 + col];
        float wb = Wb[k * 64 + col];
        a1[0] = fmaf(xa.x, wa, a1[0]); a2[0] = fmaf(xa.x, wb, a2[0]);
        a1[1] = fmaf(xa.y, wa, a1[1]); a2[1] = fmaf(xa.y, wb, a2[1]);
        a1[2] = fmaf(xa.z, wa, a1[2]); a2[2] = fmaf(xa.z, wb, a2[2]);
        a1[3] = fmaf(xa.w, wa, a1[3]); a2[3] = fmaf(xa.w, wb, a2[3]);
        a1[4] = fmaf(xb.x, wa, a1[4]); a2[4] = fmaf(xb.x, wb, a2[4]);
        a1[5] = fmaf(xb.y, wa, a1[5]); a2[5] = fmaf(xb.y, wb, a2[5]);
        a1[6] = fmaf(xb.z, wa, a1[6]); a2[6] = fmaf(xb.z, wb, a2[6]);
        a1[7] = fmaf(xb.w, wa, a1[7]); a2[7] = fmaf(xb.w, wb, a2[7]);
    }
#pragma unroll
    for (int m = 0; m < 8; ++m) {
        int row = row0 + ty * 8 + m;
        if (row < N) {
            unsigned idx = ((unsigned)row << 6) + col;
            out1[idx] = f2bf(a1[m]);
            out2[idx] = a2[m];
        }
    }
}

// ---------------- hierarchical scan, stage 1: per-block sums
__global__ __launch_bounds__(1024) void scan_blocks(const int* __restrict__ degi,
                                                    int* __restrict__ partial) {
    __shared__ int wsum[16];
    const int t = threadIdx.x;
    const int i = blockIdx.x * 1024 + t;
    const int lane = t & 63, w = t >> 6;
    int v = (i < N_NODES) ? degi[i] : 0;
#pragma unroll
    for (int d = 32; d; d >>= 1) v += __shfl_xor(v, d, 64);
    if (lane == 0) wsum[w] = v;
    __syncthreads();
    if (t == 0) {
        int s = 0;
#pragma unroll
        for (int k = 0; k < 16; ++k) s += wsum[k];
        partial[blockIdx.x] = s;
    }
}

// ---------------- stage 2: exclusive scan of 49 partials (one wave)
__global__ __launch_bounds__(64) void scan_tops(const int* __restrict__ partial,
                                                int* __restrict__ base) {
    const int t = threadIdx.x;
    int v = (t < SCAN_BLOCKS) ? partial[t] : 0;
    int inc = v;
#pragma unroll
    for (int d = 1; d < 64; d <<= 1) {
        int u = __shfl_up(inc, d, 64);
        if (t >= d) inc += u;
    }
    if (t < SCAN_BLOCKS) base[t] = inc - v;
}

// ---------------- stage 3: per-block exclusive scan + base, coalesced writes
__global__ __launch_bounds__(1024) void scan_final(const int* __restrict__ degi,
                                                   const int* __restrict__ base,
                                                   int* __restrict__ off,
                                                   int* __restrict__ cursor) {
    __shared__ int wsum[16];
    const int t = threadIdx.x;
    const int i = blockIdx.x * 1024 + t;
    const int lane = t & 63, w = t >> 6;
    int v = (i < N_NODES) ? degi[i] : 0;
    int inc = v;
#pragma unroll
    for (int d = 1; d < 64; d <<= 1) {
        int u = __shfl_up(inc, d, 64);
        if (lane >= d) inc += u;
    }
    if (lane == 63) wsum[w] = inc;
    __syncthreads();
    if (w == 0) {
        int s = (lane < 16) ? wsum[lane] : 0;
#pragma unroll
        for (int d = 1; d < 16; d <<= 1) {
            int u = __shfl_up(s, d, 64);
            if (lane >= d) s += u;
        }
        if (lane < 16) wsum[lane] = s;   // inclusive wave sums
    }
    __syncthreads();
    const int wbase = (w > 0) ? wsum[w - 1] : 0;
    const int excl = base[blockIdx.x] + wbase + inc - v;
    if (i < N_NODES) { off[i] = excl; cursor[i] = excl; }
    if (i == N_NODES) off[i] = excl;     // total edge count
}

// ---------------- CSR build: windowed scatter (pass-major grid)
__global__ __launch_bounds__(256) void fill_csr_win(const int* __restrict__ src,
                                                    const int* __restrict__ dst,
                                                    int* __restrict__ cursor,
                                                    int* __restrict__ csr) {
    int w = blockIdx.x / DEG_BLOCKS;
    int chunk = blockIdx.x % DEG_BLOCKS;
    int e = chunk * 256 + threadIdx.x;
    int d = dst[e];
    int lo = w * (N_NODES / NWIN);
    int hi = lo + (N_NODES / NWIN);
    if (d >= lo && d < hi) {
        int p = atomicAdd(&cursor[d], 1);
        csr[p] = src[e];
    }
}

// ---------------- fused gather + dual GEMM: per 32-node block,
//   h = ReLU(mean_{s in N(d)} y[s] + bias + r)  (into LDS, transposed)
//   out1 = h @ Wa, out2 = h @ Wb
template <bool OUT1_BF, bool OUT2_BF>
__global__ __launch_bounds__(256) void gather_mm(const bf16* __restrict__ y,
                                                 const float* __restrict__ r,
                                                 const int* __restrict__ csr,
                                                 const int* __restrict__ off,
                                                 const float* __restrict__ bias,
                                                 const float* __restrict__ Wa,
                                                 const float* __restrict__ Wb,
                                                 void* __restrict__ out1v,
                                                 void* __restrict__ out2v, int N) {
    constexpr int K = 64, ROWS = 32, PAD = 36;
    __shared__ float xs[K * PAD];
    const int row0 = blockIdx.x * ROWS;
    const int j  = threadIdx.x & 63;
    const int wv = threadIdx.x >> 6;
    const float bj = bias[j];

    // ---- gather phase: wave wv produces rows wv*8 .. wv*8+7
    for (int m = 0; m < 8; ++m) {
        int lr = wv * 8 + m;
        int node = row0 + lr;
        float val = 0.f;
        if (node < N) {
            int s0 = off[node], s1 = off[node + 1];
            float acc = 0.f;
            int k = s0;
            for (; k + 15 < s1; k += 16) {
                int sidx[16];
#pragma unroll
                for (int u = 0; u < 16; ++u) sidx[u] = csr[k + u];
                float v[16];
#pragma unroll
                for (int u = 0; u < 16; ++u) v[u] = bf2f(y[((unsigned)sidx[u] << 6) + j]);
                float s = 0.f;
#pragma unroll
                for (int u = 0; u < 16; ++u) s += v[u];
                acc += s;
            }
            for (; k + 3 < s1; k += 4) {
                int sa = csr[k], sb = csr[k + 1], sc = csr[k + 2], sd = csr[k + 3];
                float va = bf2f(y[((unsigned)sa << 6) + j]);
                float vb = bf2f(y[((unsigned)sb << 6) + j]);
                float vc = bf2f(y[((unsigned)sc << 6) + j]);
                float vd = bf2f(y[((unsigned)sd << 6) + j]);
                acc += (va + vb) + (vc + vd);
            }
            for (; k < s1; ++k)
                acc += bf2f(y[((unsigned)csr[k] << 6) + j]);
            float mean = acc / fmaxf((float)(s1 - s0), 1.f);
            val = fmaxf(mean + bj + r[((unsigned)node << 6) + j], 0.f);
        }
        xs[j * PAD + lr] = val;     // transposed for GEMM
    }
    __syncthreads();

    // ---- GEMM phase
    float a1[8], a2[8];
#pragma unroll
    for (int m = 0; m < 8; ++m) { a1[m] = 0.f; a2[m] = 0.f; }
#pragma unroll 4
    for (int k = 0; k < K; ++k) {
        const float4* xr = (const float4*)(xs + k * PAD + wv * 8);
        float4 xa = xr[0], xb = xr[1];
        float wa = Wa[k * 64 + j];
        float wb = Wb[k * 64 + j];
        a1[0] = fmaf(xa.x, wa, a1[0]); a2[0] = fmaf(xa.x, wb, a2[0]);
        a1[1] = fmaf(xa.y, wa, a1[1]); a2[1] = fmaf(xa.y, wb, a2[1]);
        a1[2] = fmaf(xa.z, wa, a1[2]); a2[2] = fmaf(xa.z, wb, a2[2]);
        a1[3] = fmaf(xa.w, wa, a1[3]); a2[3] = fmaf(xa.w, wb, a2[3]);
        a1[4] = fmaf(xb.x, wa, a1[4]); a2[4] = fmaf(xb.x, wb, a2[4]);
        a1[5] = fmaf(xb.y, wa, a1[5]); a2[5] = fmaf(xb.y, wb, a2[5]);
        a1[6] = fmaf(xb.z, wa, a1[6]); a2[6] = fmaf(xb.z, wb, a2[6]);
        a1[7] = fmaf(xb.w, wa, a1[7]); a2[7] = fmaf(xb.w, wb, a2[7]);
    }
#pragma unroll
    for (int m = 0; m < 8; ++m) {
        int row = row0 + wv * 8 + m;
        if (row < N) {
            unsigned idx = ((unsigned)row << 6) + j;
            if (OUT1_BF) ((bf16*)out1v)[idx] = f2bf(a1[m]);
            else         ((float*)out1v)[idx] = a1[m];
            if (OUT2_BF) ((bf16*)out2v)[idx] = f2bf(a2[m]);
            else         ((float*)out2v)[idx] = a2[m];
        }
    }
}

// merge step for batched reduction
__device__ __forceinline__ float merge_pair(float lo, float hi, int o, bool bit) {
    float keep = bit ? hi : lo;
    float send = bit ? lo : hi;
    return keep + __shfl_xor(send, o, 64);
}

// ---------------- fused edge stage: per-edge MLP, ea-projection via v_dot2_f32_f16
__global__ __launch_bounds__(256) void edge_fused(const bf16* __restrict__ aE,
                                                  const bf16* __restrict__ bE,
                                                  const float* __restrict__ ea,
                                                  const float* __restrict__ Wbot,
                                                  const float* __restrict__ bm1,
                                                  const float* __restrict__ wm2,
                                                  const float* __restrict__ bm2,
                                                  const int* __restrict__ src,
                                                  const int* __restrict__ dst,
                                                  float* __restrict__ out) {
    __shared__ unsigned ea_s[EBLK * 8];  // ea rows packed as half2 (2 KB)
    __shared__ int      sd_s[2 * EBLK];
    const int t   = threadIdx.x;
    const int eb0 = blockIdx.x * EBLK;
    const int j   = t & 63;
    const int wv  = t >> 6;

    {   // stage ea -> f16 pairs (coalesced float2 reads)
        const float2* eaf2 = (const float2*)(ea + (size_t)eb0 * 16);
        for (int i = t; i < EBLK * 8; i += 256) {
            float2 f = eaf2[i];
            half2t p;
            p.x = (_Float16)f.x;
            p.y = (_Float16)f.y;
            ea_s[i] = __builtin_bit_cast(unsigned, p);
        }
    }
    if (t < 2 * EBLK)
        sd_s[t] = (t < EBLK) ? src[eb0 + t] : dst[eb0 + t - EBLK];

    half2t wh[8];
#pragma unroll
    for (int kk = 0; kk < 8; ++kk) {
        wh[kk].x = (_Float16)Wbot[(2 * kk) * 64 + j];
        wh[kk].y = (_Float16)Wbot[(2 * kk + 1) * 64 + j];
    }
    const float bm1c = bm1[j];
    const float wm2c = wm2[j];
    const float bm2c = bm2[0];
    const bool b5 = (j & 32) != 0, b4 = (j & 16) != 0, b3 = (j & 8) != 0;
    __syncthreads();

    const ushort* aU = (const ushort*)aE;
    const ushort* bU = (const ushort*)bE;

    for (int g = 0; g < 2; ++g) {
        const int ebase = wv * 16 + g * 8;
        ushort av[8], bv[8];
#pragma unroll
        for (int u = 0; u < 8; ++u) {
            int e = ebase + u;
            av[u] = aU[((unsigned)sd_s[e] << 6) + j];
            bv[u] = bU[((unsigned)sd_s[EBLK + e] << 6) + j];
        }
        float p[8];
#pragma unroll
        for (int u = 0; u < 8; ++u) {
            const uint4* er = (const uint4*)(ea_s + (ebase + u) * 8);
            uint4 qa = er[0], qb = er[1];
            float v = bm1c;
            v = __builtin_amdgcn_fdot2(__builtin_bit_cast(half2t, qa.x), wh[0], v, false);
            v = __builtin_amdgcn_fdot2(__builtin_bit_cast(half2t, qa.y), wh[1], v, false);
            v = __builtin_amdgcn_fdot2(__builtin_bit_cast(half2t, qa.z), wh[2], v, false);
            v = __builtin_amdgcn_fdot2(__builtin_bit_cast(half2t, qa.w), wh[3], v, false);
            v = __builtin_amdgcn_fdot2(__builtin_bit_cast(half2t, qb.x), wh[4], v, false);
            v = __builtin_amdgcn_fdot2(__builtin_bit_cast(half2t, qb.y), wh[5], v, false);
            v = __builtin_amdgcn_fdot2(__builtin_bit_cast(half2t, qb.z), wh[6], v, false);
            v = __builtin_amdgcn_fdot2(__builtin_bit_cast(half2t, qb.w), wh[7], v, false);
            bf16 ab = *(const bf16*)&av[u];
            bf16 bb = *(const bf16*)&bv[u];
            v += bf2f(ab) + bf2f(bb);
            p[u] = fmaxf(v, 0.f) * wm2c;
        }
        float q0 = merge_pair(p[0], p[1], 32, b5);
        float q1 = merge_pair(p[2], p[3], 32, b5);
        float q2 = merge_pair(p[4], p[5], 32, b5);
        float q3 = merge_pair(p[6], p[7], 32, b5);
        float r0 = merge_pair(q0, q1, 16, b4);
        float r1 = merge_pair(q2, q3, 16, b4);
        float s  = merge_pair(r0, r1, 8, b3);
        s += __shfl_xor(s, 4, 64);
        s += __shfl_xor(s, 2, 64);
        s += __shfl_xor(s, 1, 64);
        if ((j & 7) == 0) {
            int m = 4 * ((j >> 3) & 1) + 2 * ((j >> 4) & 1) + ((j >> 5) & 1);
            out[eb0 + ebase + m] = 1.f / (1.f + __expf(-(s + bm2c)));
        }
    }
}

extern "C" void kernel_launch(void* const* d_in, const int* in_sizes, int n_in,
                              void* d_out, int out_size, void* d_ws, size_t ws_size,
                              hipStream_t stream) {
    const float* x         = (const float*)d_in[0];
    const float* edge_attr = (const float*)d_in[1];
    const float* W1l       = (const float*)d_in[2];
    const float* b1l       = (const float*)d_in[3];
    const float* W1r       = (const float*)d_in[4];
    const float* W2l       = (const float*)d_in[5];
    const float* b2l       = (const float*)d_in[6];
    const float* W2r       = (const float*)d_in[7];
    const float* Wm1       = (const float*)d_in[8];
    const float* bm1       = (const float*)d_in[9];
    const float* Wm2       = (const float*)d_in[10];
    const float* bm2       = (const float*)d_in[11];
    const int*   ei        = (const int*)d_in[12];   // [2, E] int32
    const int*   src       = ei;
    const int*   dst       = ei + N_EDGES;
    float* out = (float*)d_out;

    // workspace words: degi 50176 | off 50432 | cursor 50176 (50000 used;
    //   +50000: partial[64], +50064: base[64]) | csr 1.6M |
    //   bfA/bfB/bfC (bf16 x 3.2M = 1.6M words each) | fR 3.2M | fR2 3.2M
    int*   degi    = (int*)d_ws;
    int*   off     = degi + 50176;
    int*   cursor  = off + 50432;
    int*   partial = cursor + 50000;
    int*   base    = cursor + 50064;
    int*   csr     = cursor + 50176;
    bf16*  bfA     = (bf16*)(csr + N_EDGES);  // y1 / aE
    bf16*  bfB     = bfA + NODEF;             // y2
    bf16*  bfC     = bfB + NODEF;             // bE
    float* fR      = (float*)(bfC + NODEF);   // r1
    float* fR2     = fR + NODEF;              // r2

    const int N = N_NODES, E = N_EDGES;
    const int mmGrid = (N + 31) / 32;        // 1563 == MM1_BLOCKS
    const int efGrid = E / EBLK;

    // ---- conv1 GEMM + degree count fused (deg hides under GEMM)
    hipMemsetAsync(degi, 0, N_NODES * sizeof(int), stream);
    conv1_and_deg<<<MM1_BLOCKS + DEG_BLOCKS, 256, 0, stream>>>(
        x, W1l, W1r, bfA, fR, dst, degi, N, E);

    // ---- CSR offsets: hierarchical scan (all stages parallel)
    scan_blocks<<<SCAN_BLOCKS, 1024, 0, stream>>>(degi, partial);
    scan_tops<<<1, 64, 0, stream>>>(partial, base);
    scan_final<<<SCAN_BLOCKS, 1024, 0, stream>>>(degi, base, off, cursor);

    fill_csr_win<<<NWIN * DEG_BLOCKS, 256, 0, stream>>>(src, dst, cursor, csr);

    // ---- conv2: gather h1 (from y1,r1) fused with y2 = h1@W2l, r2 = h1@W2r
    gather_mm<true, false><<<mmGrid, 256, 0, stream>>>(
        bfA, fR, csr, off, b1l, W2l, W2r, bfB, fR2, N);

    // ---- edge precompute: gather h2 (from y2,r2) fused with aE/bE = h2@Wm1 halves
    gather_mm<true, true><<<mmGrid, 256, 0, stream>>>(
        bfB, fR2, csr, off, b2l, Wm1, Wm1 + 64 * 64, bfA, bfC, N);

    // ---- fused edge MLP
    edge_fused<<<efGrid, 256, 0, stream>>>(bfA, bfC, edge_attr, Wm1 + 128 * 64,
                                           bm1, Wm2, bm2, src, dst, out);
}